// Round 1
// baseline (1818.568 us; speedup 1.0000x reference)
//
#include <hip/hip_runtime.h>

#define NN 50000
#define NE 800000
#define C 128

__device__ __forceinline__ float wave_sum(float v) {
#pragma unroll
    for (int off = 32; off > 0; off >>= 1) v += __shfl_xor(v, off, 64);
    return v;
}

// ---------------- CSR build ----------------
__global__ void count_deg(const int* __restrict__ row, int* __restrict__ deg) {
    int e = blockIdx.x * blockDim.x + threadIdx.x;
    if (e < NE) atomicAdd(&deg[row[e]], 1);
}

__global__ void scan_deg(const int* __restrict__ deg, int* __restrict__ offsets,
                         int* __restrict__ cursor) {
    __shared__ int part[1024];
    int t = threadIdx.x;
    const int CHUNK = (NN + 1023) / 1024;
    int base = t * CHUNK;
    int s = 0;
    for (int i = 0; i < CHUNK; ++i) {
        int idx = base + i;
        if (idx < NN) s += deg[idx];
    }
    part[t] = s;
    __syncthreads();
    for (int off = 1; off < 1024; off <<= 1) {
        int v = part[t];
        int add = (t >= off) ? part[t - off] : 0;
        __syncthreads();
        part[t] = v + add;
        __syncthreads();
    }
    int run = (t == 0) ? 0 : part[t - 1];
    for (int i = 0; i < CHUNK; ++i) {
        int idx = base + i;
        if (idx < NN) {
            offsets[idx] = run;
            cursor[idx] = run;
            run += deg[idx];
        }
    }
    if (t == 1023) offsets[NN] = part[1023];
}

__global__ void bucket_edges(const int* __restrict__ row, int* __restrict__ cursor,
                             int* __restrict__ perm) {
    int e = blockIdx.x * blockDim.x + threadIdx.x;
    if (e < NE) {
        int p = atomicAdd(&cursor[row[e]], 1);
        perm[p] = e;
    }
}

// ---------------- per-node squared norms ----------------
__global__ void norm2_kernel(const float* __restrict__ x, float* __restrict__ out) {
    int node = blockIdx.x * 4 + (threadIdx.x >> 6);
    int lane = threadIdx.x & 63;
    const float2 v = *(const float2*)(x + (size_t)node * C + lane * 2);
    float s = wave_sum(v.x * v.x + v.y * v.y);
    if (lane == 0) out[node] = s;
}

// ---------------- layer-1 fused similarity + aggregation ----------------
// aggc[n] = mean_e cos(x[n],x[col]) * x[col] ; agge[n] = mean_e ||x[n]-x[col]+eps|| * x[col]
__global__ void l1_agg(const float* __restrict__ x, const int* __restrict__ col,
                       const int* __restrict__ perm, const int* __restrict__ offsets,
                       const float* __restrict__ n2, float* __restrict__ aggc,
                       float* __restrict__ agge) {
    int node = blockIdx.x * 4 + (threadIdx.x >> 6);
    int lane = threadIdx.x & 63;
    const float2 xa = *(const float2*)(x + (size_t)node * C + lane * 2);
    float na2 = n2[node];
    int beg = offsets[node], end = offsets[node + 1];
    float ac0 = 0.f, ac1 = 0.f, ae0 = 0.f, ae1 = 0.f;
    for (int p = beg; p < end; ++p) {
        int c = col[perm[p]];
        const float2 xb = *(const float2*)(x + (size_t)c * C + lane * 2);
        float dp = xa.x * xb.x + xa.y * xb.y;
        float d0 = xa.x - xb.x + 1e-6f;
        float d1 = xa.y - xb.y + 1e-6f;
        float ep = d0 * d0 + d1 * d1;
#pragma unroll
        for (int off = 32; off > 0; off >>= 1) {
            dp += __shfl_xor(dp, off, 64);
            ep += __shfl_xor(ep, off, 64);
        }
        float wc = dp / fmaxf(sqrtf(na2 * n2[c]), 1e-8f);
        float we = sqrtf(ep);
        ac0 += wc * xb.x; ac1 += wc * xb.y;
        ae0 += we * xb.x; ae1 += we * xb.y;
    }
    float inv = 1.f / fmaxf((float)(end - beg), 1.f);
    *(float2*)(aggc + (size_t)node * C + lane * 2) = make_float2(ac0 * inv, ac1 * inv);
    *(float2*)(agge + (size_t)node * C + lane * 2) = make_float2(ae0 * inv, ae1 * inv);
}

// ---------------- layer-2 fused similarity + aggregation ----------------
// agg1 from x3 with cos weights ; agg2 from x4 with euclid weights
__global__ void l2_agg(const float* __restrict__ x3, const float* __restrict__ x4,
                       const int* __restrict__ col, const int* __restrict__ perm,
                       const int* __restrict__ offsets, const float* __restrict__ n2_3,
                       float* __restrict__ agg1, float* __restrict__ agg2) {
    int node = blockIdx.x * 4 + (threadIdx.x >> 6);
    int lane = threadIdx.x & 63;
    const float2 a3 = *(const float2*)(x3 + (size_t)node * C + lane * 2);
    const float2 a4 = *(const float2*)(x4 + (size_t)node * C + lane * 2);
    float na2 = n2_3[node];
    int beg = offsets[node], end = offsets[node + 1];
    float p10 = 0.f, p11 = 0.f, p20 = 0.f, p21 = 0.f;
    for (int p = beg; p < end; ++p) {
        int c = col[perm[p]];
        const float2 b3 = *(const float2*)(x3 + (size_t)c * C + lane * 2);
        const float2 b4 = *(const float2*)(x4 + (size_t)c * C + lane * 2);
        float dp = a3.x * b3.x + a3.y * b3.y;
        float d0 = a4.x - b4.x + 1e-6f;
        float d1 = a4.y - b4.y + 1e-6f;
        float ep = d0 * d0 + d1 * d1;
#pragma unroll
        for (int off = 32; off > 0; off >>= 1) {
            dp += __shfl_xor(dp, off, 64);
            ep += __shfl_xor(ep, off, 64);
        }
        float wc = dp / fmaxf(sqrtf(na2 * n2_3[c]), 1e-8f);
        float we = sqrtf(ep);
        p10 += wc * b3.x; p11 += wc * b3.y;
        p20 += we * b4.x; p21 += we * b4.y;
    }
    float inv = 1.f / fmaxf((float)(end - beg), 1.f);
    *(float2*)(agg1 + (size_t)node * C + lane * 2) = make_float2(p10 * inv, p11 * inv);
    *(float2*)(agg2 + (size_t)node * C + lane * 2) = make_float2(p20 * inv, p21 * inv);
}

// ---------------- layer-1 GEMM: x3 = relu(aggc@Wl + x@Wr + bl), x4 = relu(agge@Wl + x@Wr + bl)
__global__ __launch_bounds__(256) void gemm1(
    const float* __restrict__ aggc, const float* __restrict__ agge, const float* __restrict__ x,
    const float* __restrict__ Wl, const float* __restrict__ Wr, const float* __restrict__ bl,
    float* __restrict__ x3, float* __restrict__ x4) {
    __shared__ __align__(16) float sWl[32 * 128];
    __shared__ __align__(16) float sWr[32 * 128];
    int j = threadIdx.x & 127;
    int h = threadIdx.x >> 7;
    int n0 = blockIdx.x * 16 + h * 8;
    float tv[8] = {}, m3[8] = {}, m4[8] = {};
    for (int kc = 0; kc < 128; kc += 32) {
        const float4* gl = (const float4*)(Wl + kc * 128);
        const float4* gr = (const float4*)(Wr + kc * 128);
        float4* sl = (float4*)sWl;
        float4* sr = (float4*)sWr;
        for (int idx = threadIdx.x; idx < 1024; idx += 256) { sl[idx] = gl[idx]; sr[idx] = gr[idx]; }
        __syncthreads();
#pragma unroll
        for (int kk = 0; kk < 32; kk += 4) {
            float wl0 = sWl[(kk + 0) * 128 + j], wl1 = sWl[(kk + 1) * 128 + j];
            float wl2 = sWl[(kk + 2) * 128 + j], wl3 = sWl[(kk + 3) * 128 + j];
            float wr0 = sWr[(kk + 0) * 128 + j], wr1 = sWr[(kk + 1) * 128 + j];
            float wr2 = sWr[(kk + 2) * 128 + j], wr3 = sWr[(kk + 3) * 128 + j];
#pragma unroll
            for (int i = 0; i < 8; ++i) {
                size_t base = (size_t)(n0 + i) * C + kc + kk;
                float4 a = *(const float4*)(aggc + base);
                float4 b = *(const float4*)(agge + base);
                float4 xv = *(const float4*)(x + base);
                m3[i] += a.x * wl0 + a.y * wl1 + a.z * wl2 + a.w * wl3;
                m4[i] += b.x * wl0 + b.y * wl1 + b.z * wl2 + b.w * wl3;
                tv[i] += xv.x * wr0 + xv.y * wr1 + xv.z * wr2 + xv.w * wr3;
            }
        }
        __syncthreads();
    }
    float blj = bl[j];
#pragma unroll
    for (int i = 0; i < 8; ++i) {
        size_t o = (size_t)(n0 + i) * C + j;
        x3[o] = fmaxf(tv[i] + m3[i] + blj, 0.f);
        x4[o] = fmaxf(tv[i] + m4[i] + blj, 0.f);
    }
}

// ---------------- layer-2 GEMM: y1 = agg1@Wl + x3@Wr + bl, y2 = agg2@Wl + x4@Wr + bl
__global__ __launch_bounds__(256) void gemm2(
    const float* __restrict__ agg1, const float* __restrict__ agg2,
    const float* __restrict__ x3, const float* __restrict__ x4,
    const float* __restrict__ Wl, const float* __restrict__ Wr, const float* __restrict__ bl,
    float* __restrict__ y1, float* __restrict__ y2) {
    __shared__ __align__(16) float sWl[32 * 128];
    __shared__ __align__(16) float sWr[32 * 128];
    int j = threadIdx.x & 127;
    int h = threadIdx.x >> 7;
    int n0 = blockIdx.x * 16 + h * 8;
    float p1[8] = {}, p2[8] = {};
    for (int kc = 0; kc < 128; kc += 32) {
        const float4* gl = (const float4*)(Wl + kc * 128);
        const float4* gr = (const float4*)(Wr + kc * 128);
        float4* sl = (float4*)sWl;
        float4* sr = (float4*)sWr;
        for (int idx = threadIdx.x; idx < 1024; idx += 256) { sl[idx] = gl[idx]; sr[idx] = gr[idx]; }
        __syncthreads();
#pragma unroll
        for (int kk = 0; kk < 32; kk += 4) {
            float wl0 = sWl[(kk + 0) * 128 + j], wl1 = sWl[(kk + 1) * 128 + j];
            float wl2 = sWl[(kk + 2) * 128 + j], wl3 = sWl[(kk + 3) * 128 + j];
            float wr0 = sWr[(kk + 0) * 128 + j], wr1 = sWr[(kk + 1) * 128 + j];
            float wr2 = sWr[(kk + 2) * 128 + j], wr3 = sWr[(kk + 3) * 128 + j];
#pragma unroll
            for (int i = 0; i < 8; ++i) {
                size_t base = (size_t)(n0 + i) * C + kc + kk;
                float4 a1 = *(const float4*)(agg1 + base);
                float4 a2 = *(const float4*)(agg2 + base);
                float4 v3 = *(const float4*)(x3 + base);
                float4 v4 = *(const float4*)(x4 + base);
                p1[i] += a1.x * wl0 + a1.y * wl1 + a1.z * wl2 + a1.w * wl3
                       + v3.x * wr0 + v3.y * wr1 + v3.z * wr2 + v3.w * wr3;
                p2[i] += a2.x * wl0 + a2.y * wl1 + a2.z * wl2 + a2.w * wl3
                       + v4.x * wr0 + v4.y * wr1 + v4.z * wr2 + v4.w * wr3;
            }
        }
        __syncthreads();
    }
    float blj = bl[j];
#pragma unroll
    for (int i = 0; i < 8; ++i) {
        size_t o = (size_t)(n0 + i) * C + j;
        y1[o] = p1[i] + blj;
        y2[o] = p2[i] + blj;
    }
}

// ---------------- attention pooling ----------------
__global__ __launch_bounds__(256) void attention(
    const float* x1, const float* x2, const float* x3, const float* x4,
    const float* __restrict__ W1, const float* __restrict__ b1, const float* __restrict__ W2,
    float* emb) {
    __shared__ __align__(16) float sW1[128 * 64];
    __shared__ float sb1[64];
    __shared__ float sW2[64];
    {
        const float4* g = (const float4*)W1;
        float4* s = (float4*)sW1;
        for (int idx = threadIdx.x; idx < 2048; idx += 256) s[idx] = g[idx];
        if (threadIdx.x < 64) {
            sb1[threadIdx.x] = b1[threadIdx.x];
            sW2[threadIdx.x] = W2[threadIdx.x];
        }
    }
    __syncthreads();
    int node = blockIdx.x * 4 + (threadIdx.x >> 6);
    int lane = threadIdx.x & 63;
    const float* zs[4] = {x1 + (size_t)node * C, x2 + (size_t)node * C,
                          x3 + (size_t)node * C, x4 + (size_t)node * C};
    float w[4];
#pragma unroll
    for (int br = 0; br < 4; ++br) {
        float hj = sb1[lane];
        for (int k = 0; k < 128; k += 4) {
            float4 z4 = *(const float4*)(zs[br] + k);
            hj += z4.x * sW1[(k + 0) * 64 + lane] + z4.y * sW1[(k + 1) * 64 + lane]
                + z4.z * sW1[(k + 2) * 64 + lane] + z4.w * sW1[(k + 3) * 64 + lane];
        }
        float cl = fminf(fmaxf(hj, -15.f), 15.f);
        float e2 = __expf(2.f * cl);
        float th = (e2 - 1.f) / (e2 + 1.f);
        w[br] = wave_sum(th * sW2[lane]);
    }
    float m = fmaxf(fmaxf(w[0], w[1]), fmaxf(w[2], w[3]));
    float e0 = __expf(w[0] - m), e1 = __expf(w[1] - m);
    float e2b = __expf(w[2] - m), e3 = __expf(w[3] - m);
    float inv = 1.f / (e0 + e1 + e2b + e3);
    float b0 = e0 * inv, bb1 = e1 * inv, b2 = e2b * inv, b3 = e3 * inv;
#pragma unroll
    for (int part = 0; part < 2; ++part) {
        int ch = lane + part * 64;
        float v = b0 * zs[0][ch] + bb1 * zs[1][ch] + b2 * zs[2][ch] + b3 * zs[3][ch];
        emb[(size_t)node * C + ch] = v;
    }
}

extern "C" void kernel_launch(void* const* d_in, const int* in_sizes, int n_in,
                              void* d_out, int out_size, void* d_ws, size_t ws_size,
                              hipStream_t stream) {
    const float* x   = (const float*)d_in[0];
    const int* row   = (const int*)d_in[1];
    const int* col   = (const int*)d_in[2];
    const float* Wl0 = (const float*)d_in[3];
    const float* bl0 = (const float*)d_in[4];
    const float* Wr0 = (const float*)d_in[5];
    const float* Wl1 = (const float*)d_in[6];
    const float* bl1 = (const float*)d_in[7];
    const float* Wr1 = (const float*)d_in[8];
    const float* aW1 = (const float*)d_in[9];
    const float* ab1 = (const float*)d_in[10];
    const float* aW2 = (const float*)d_in[11];

    float* out = (float*)d_out;
    float* emb = out;                         // also reused as x1 scratch (disjoint per node, written last)
    float* x3  = out + (size_t)NN * C;
    float* x4  = out + 2 * (size_t)NN * C;

    char* ws = (char*)d_ws;
    size_t off = 0;
    auto alloc = [&](size_t bytes) -> void* {
        void* p = ws + off;
        off += (bytes + 255) & ~(size_t)255;
        return p;
    };
    int* deg     = (int*)alloc((size_t)NN * 4);
    int* offsets = (int*)alloc((size_t)(NN + 1) * 4);
    int* cursor  = (int*)alloc((size_t)NN * 4);
    int* perm    = (int*)alloc((size_t)NE * 4);
    float* n2    = (float*)alloc((size_t)NN * 4);
    float* n2b   = (float*)alloc((size_t)NN * 4);
    float* bufA  = (float*)alloc((size_t)NN * C * 4);   // aggc -> agg1
    float* bufB  = (float*)alloc((size_t)NN * C * 4);   // agge -> agg2
    float* bufC  = (float*)alloc((size_t)NN * C * 4);   // x2

    hipMemsetAsync(deg, 0, (size_t)NN * 4, stream);
    count_deg<<<(NE + 255) / 256, 256, 0, stream>>>(row, deg);
    scan_deg<<<1, 1024, 0, stream>>>(deg, offsets, cursor);
    bucket_edges<<<(NE + 255) / 256, 256, 0, stream>>>(row, cursor, perm);

    norm2_kernel<<<NN / 4, 256, 0, stream>>>(x, n2);
    l1_agg<<<NN / 4, 256, 0, stream>>>(x, col, perm, offsets, n2, bufA, bufB);
    gemm1<<<NN / 16, 256, 0, stream>>>(bufA, bufB, x, Wl0, Wr0, bl0, x3, x4);

    norm2_kernel<<<NN / 4, 256, 0, stream>>>(x3, n2b);
    l2_agg<<<NN / 4, 256, 0, stream>>>(x3, x4, col, perm, offsets, n2b, bufA, bufB);
    gemm2<<<NN / 16, 256, 0, stream>>>(bufA, bufB, x3, x4, Wl1, Wr1, bl1, emb /*x1*/, bufC /*x2*/);

    attention<<<NN / 4, 256, 0, stream>>>(emb /*x1*/, bufC /*x2*/, x3, x4, aW1, ab1, aW2, out);
}

// Round 2
// 1435.302 us; speedup vs baseline: 1.2670x; 1.2670x over previous
//
#include <hip/hip_runtime.h>

#define NN 50000
#define NE 800000
#define C 128

__device__ __forceinline__ float wave_sum(float v) {
#pragma unroll
    for (int off = 32; off > 0; off >>= 1) v += __shfl_xor(v, off, 64);
    return v;
}

// ---------------- CSR build ----------------
__global__ void count_deg(const int* __restrict__ row, int* __restrict__ deg) {
    int e = blockIdx.x * blockDim.x + threadIdx.x;
    if (e < NE) atomicAdd(&deg[row[e]], 1);
}

__global__ void scan_deg(const int* __restrict__ deg, int* __restrict__ offsets,
                         int* __restrict__ cursor) {
    __shared__ int part[1024];
    int t = threadIdx.x;
    const int CHUNK = (NN + 1023) / 1024;
    int base = t * CHUNK;
    int s = 0;
    for (int i = 0; i < CHUNK; ++i) {
        int idx = base + i;
        if (idx < NN) s += deg[idx];
    }
    part[t] = s;
    __syncthreads();
    for (int off = 1; off < 1024; off <<= 1) {
        int v = part[t];
        int add = (t >= off) ? part[t - off] : 0;
        __syncthreads();
        part[t] = v + add;
        __syncthreads();
    }
    int run = (t == 0) ? 0 : part[t - 1];
    for (int i = 0; i < CHUNK; ++i) {
        int idx = base + i;
        if (idx < NN) {
            offsets[idx] = run;
            cursor[idx] = run;
            run += deg[idx];
        }
    }
    if (t == 1023) offsets[NN] = part[1023];
}

__global__ void bucket_edges(const int* __restrict__ row, int* __restrict__ cursor,
                             int* __restrict__ perm) {
    int e = blockIdx.x * blockDim.x + threadIdx.x;
    if (e < NE) {
        int p = atomicAdd(&cursor[row[e]], 1);
        perm[p] = e;
    }
}

// ---------------- per-node squared norms ----------------
__global__ void norm2_kernel(const float* __restrict__ x, float* __restrict__ out) {
    int node = blockIdx.x * 4 + (threadIdx.x >> 6);
    int lane = threadIdx.x & 63;
    const float2 v = *(const float2*)(x + (size_t)node * C + lane * 2);
    float s = wave_sum(v.x * v.x + v.y * v.y);
    if (lane == 0) out[node] = s;
}

// ---------------- layer-1 fused similarity + aggregation ----------------
__global__ void l1_agg(const float* __restrict__ x, const int* __restrict__ col,
                       const int* __restrict__ perm, const int* __restrict__ offsets,
                       const float* __restrict__ n2, float* __restrict__ aggc,
                       float* __restrict__ agge) {
    int node = blockIdx.x * 4 + (threadIdx.x >> 6);
    int lane = threadIdx.x & 63;
    const float2 xa = *(const float2*)(x + (size_t)node * C + lane * 2);
    float na2 = n2[node];
    int beg = offsets[node], end = offsets[node + 1];
    float ac0 = 0.f, ac1 = 0.f, ae0 = 0.f, ae1 = 0.f;
    for (int p = beg; p < end; ++p) {
        int c = col[perm[p]];
        const float2 xb = *(const float2*)(x + (size_t)c * C + lane * 2);
        float dp = xa.x * xb.x + xa.y * xb.y;
        float d0 = xa.x - xb.x + 1e-6f;
        float d1 = xa.y - xb.y + 1e-6f;
        float ep = d0 * d0 + d1 * d1;
#pragma unroll
        for (int off = 32; off > 0; off >>= 1) {
            dp += __shfl_xor(dp, off, 64);
            ep += __shfl_xor(ep, off, 64);
        }
        float wc = dp / fmaxf(sqrtf(na2 * n2[c]), 1e-8f);
        float we = sqrtf(ep);
        ac0 += wc * xb.x; ac1 += wc * xb.y;
        ae0 += we * xb.x; ae1 += we * xb.y;
    }
    float inv = 1.f / fmaxf((float)(end - beg), 1.f);
    *(float2*)(aggc + (size_t)node * C + lane * 2) = make_float2(ac0 * inv, ac1 * inv);
    *(float2*)(agge + (size_t)node * C + lane * 2) = make_float2(ae0 * inv, ae1 * inv);
}

// ---------------- layer-2 fused similarity + aggregation ----------------
__global__ void l2_agg(const float* __restrict__ x3, const float* __restrict__ x4,
                       const int* __restrict__ col, const int* __restrict__ perm,
                       const int* __restrict__ offsets, const float* __restrict__ n2_3,
                       float* __restrict__ agg1, float* __restrict__ agg2) {
    int node = blockIdx.x * 4 + (threadIdx.x >> 6);
    int lane = threadIdx.x & 63;
    const float2 a3 = *(const float2*)(x3 + (size_t)node * C + lane * 2);
    const float2 a4 = *(const float2*)(x4 + (size_t)node * C + lane * 2);
    float na2 = n2_3[node];
    int beg = offsets[node], end = offsets[node + 1];
    float p10 = 0.f, p11 = 0.f, p20 = 0.f, p21 = 0.f;
    for (int p = beg; p < end; ++p) {
        int c = col[perm[p]];
        const float2 b3 = *(const float2*)(x3 + (size_t)c * C + lane * 2);
        const float2 b4 = *(const float2*)(x4 + (size_t)c * C + lane * 2);
        float dp = a3.x * b3.x + a3.y * b3.y;
        float d0 = a4.x - b4.x + 1e-6f;
        float d1 = a4.y - b4.y + 1e-6f;
        float ep = d0 * d0 + d1 * d1;
#pragma unroll
        for (int off = 32; off > 0; off >>= 1) {
            dp += __shfl_xor(dp, off, 64);
            ep += __shfl_xor(ep, off, 64);
        }
        float wc = dp / fmaxf(sqrtf(na2 * n2_3[c]), 1e-8f);
        float we = sqrtf(ep);
        p10 += wc * b3.x; p11 += wc * b3.y;
        p20 += we * b4.x; p21 += we * b4.y;
    }
    float inv = 1.f / fmaxf((float)(end - beg), 1.f);
    *(float2*)(agg1 + (size_t)node * C + lane * 2) = make_float2(p10 * inv, p11 * inv);
    *(float2*)(agg2 + (size_t)node * C + lane * 2) = make_float2(p20 * inv, p21 * inv);
}

// ---------------- layer-1 GEMM: LDS-staged A + W, 32 nodes/block, 2 cols/thread
__global__ __launch_bounds__(256) void gemm1(
    const float* __restrict__ aggc, const float* __restrict__ agge, const float* __restrict__ x,
    const float* __restrict__ Wl, const float* __restrict__ Wr, const float* __restrict__ bl,
    float* __restrict__ x3, float* __restrict__ x4) {
    __shared__ __align__(16) float sWl[32 * 128];
    __shared__ __align__(16) float sWr[32 * 128];
    __shared__ __align__(16) float sA[3][32][36];   // +4 pad: spread staging-write banks
    int tx = threadIdx.x;
    int j0 = tx & 63;           // cols j0, j0+64
    int h  = tx >> 6;           // node group 0..3 (8 nodes each) — wave-uniform
    int n0 = blockIdx.x * 32;
    const float* arrs[3] = {aggc, agge, x};
    float m3[8][2] = {}, m4[8][2] = {}, tv[8][2] = {};
    for (int kc = 0; kc < 128; kc += 32) {
        const float4* gl = (const float4*)(Wl + kc * 128);
        const float4* gr = (const float4*)(Wr + kc * 128);
        float4* sl = (float4*)sWl;
        float4* sr = (float4*)sWr;
        for (int idx = tx; idx < 1024; idx += 256) { sl[idx] = gl[idx]; sr[idx] = gr[idx]; }
        for (int idx = tx; idx < 768; idx += 256) {
            int arr = idx >> 8, rem = idx & 255, node = rem >> 3, quad = rem & 7;
            int n = n0 + node; if (n > NN - 1) n = NN - 1;
            *(float4*)(&sA[arr][node][quad * 4]) =
                *(const float4*)(arrs[arr] + (size_t)n * C + kc + quad * 4);
        }
        __syncthreads();
#pragma unroll
        for (int kk = 0; kk < 32; kk += 4) {
            float wl[4][2], wr[4][2];
#pragma unroll
            for (int q = 0; q < 4; ++q) {
                wl[q][0] = sWl[(kk + q) * 128 + j0];
                wl[q][1] = sWl[(kk + q) * 128 + j0 + 64];
                wr[q][0] = sWr[(kk + q) * 128 + j0];
                wr[q][1] = sWr[(kk + q) * 128 + j0 + 64];
            }
#pragma unroll
            for (int i = 0; i < 8; ++i) {
                int node = h * 8 + i;
                float4 a  = *(const float4*)(&sA[0][node][kk]);  // broadcast (wave-uniform)
                float4 b  = *(const float4*)(&sA[1][node][kk]);
                float4 xv = *(const float4*)(&sA[2][node][kk]);
#pragma unroll
                for (int cp = 0; cp < 2; ++cp) {
                    m3[i][cp] += a.x * wl[0][cp] + a.y * wl[1][cp] + a.z * wl[2][cp] + a.w * wl[3][cp];
                    m4[i][cp] += b.x * wl[0][cp] + b.y * wl[1][cp] + b.z * wl[2][cp] + b.w * wl[3][cp];
                    tv[i][cp] += xv.x * wr[0][cp] + xv.y * wr[1][cp] + xv.z * wr[2][cp] + xv.w * wr[3][cp];
                }
            }
        }
        __syncthreads();
    }
    float blj0 = bl[j0], blj1 = bl[j0 + 64];
#pragma unroll
    for (int i = 0; i < 8; ++i) {
        int n = n0 + h * 8 + i;
        if (n < NN) {
            size_t o = (size_t)n * C + j0;
            x3[o]      = fmaxf(tv[i][0] + m3[i][0] + blj0, 0.f);
            x3[o + 64] = fmaxf(tv[i][1] + m3[i][1] + blj1, 0.f);
            x4[o]      = fmaxf(tv[i][0] + m4[i][0] + blj0, 0.f);
            x4[o + 64] = fmaxf(tv[i][1] + m4[i][1] + blj1, 0.f);
        }
    }
}

// ---------------- layer-2 GEMM
__global__ __launch_bounds__(256) void gemm2(
    const float* __restrict__ agg1, const float* __restrict__ agg2,
    const float* __restrict__ x3, const float* __restrict__ x4,
    const float* __restrict__ Wl, const float* __restrict__ Wr, const float* __restrict__ bl,
    float* __restrict__ y1, float* __restrict__ y2) {
    __shared__ __align__(16) float sWl[32 * 128];
    __shared__ __align__(16) float sWr[32 * 128];
    __shared__ __align__(16) float sA[4][32][36];
    int tx = threadIdx.x;
    int j0 = tx & 63;
    int h  = tx >> 6;
    int n0 = blockIdx.x * 32;
    const float* arrs[4] = {agg1, x3, agg2, x4};
    float p1[8][2] = {}, p2[8][2] = {};
    for (int kc = 0; kc < 128; kc += 32) {
        const float4* gl = (const float4*)(Wl + kc * 128);
        const float4* gr = (const float4*)(Wr + kc * 128);
        float4* sl = (float4*)sWl;
        float4* sr = (float4*)sWr;
        for (int idx = tx; idx < 1024; idx += 256) { sl[idx] = gl[idx]; sr[idx] = gr[idx]; }
        for (int idx = tx; idx < 1024; idx += 256) {
            int arr = idx >> 8, rem = idx & 255, node = rem >> 3, quad = rem & 7;
            int n = n0 + node; if (n > NN - 1) n = NN - 1;
            *(float4*)(&sA[arr][node][quad * 4]) =
                *(const float4*)(arrs[arr] + (size_t)n * C + kc + quad * 4);
        }
        __syncthreads();
#pragma unroll
        for (int kk = 0; kk < 32; kk += 4) {
            float wl[4][2], wr[4][2];
#pragma unroll
            for (int q = 0; q < 4; ++q) {
                wl[q][0] = sWl[(kk + q) * 128 + j0];
                wl[q][1] = sWl[(kk + q) * 128 + j0 + 64];
                wr[q][0] = sWr[(kk + q) * 128 + j0];
                wr[q][1] = sWr[(kk + q) * 128 + j0 + 64];
            }
#pragma unroll
            for (int i = 0; i < 8; ++i) {
                int node = h * 8 + i;
                float4 a1 = *(const float4*)(&sA[0][node][kk]);
                float4 v3 = *(const float4*)(&sA[1][node][kk]);
                float4 a2 = *(const float4*)(&sA[2][node][kk]);
                float4 v4 = *(const float4*)(&sA[3][node][kk]);
#pragma unroll
                for (int cp = 0; cp < 2; ++cp) {
                    p1[i][cp] += a1.x * wl[0][cp] + a1.y * wl[1][cp] + a1.z * wl[2][cp] + a1.w * wl[3][cp]
                               + v3.x * wr[0][cp] + v3.y * wr[1][cp] + v3.z * wr[2][cp] + v3.w * wr[3][cp];
                    p2[i][cp] += a2.x * wl[0][cp] + a2.y * wl[1][cp] + a2.z * wl[2][cp] + a2.w * wl[3][cp]
                               + v4.x * wr[0][cp] + v4.y * wr[1][cp] + v4.z * wr[2][cp] + v4.w * wr[3][cp];
                }
            }
        }
        __syncthreads();
    }
    float blj0 = bl[j0], blj1 = bl[j0 + 64];
#pragma unroll
    for (int i = 0; i < 8; ++i) {
        int n = n0 + h * 8 + i;
        if (n < NN) {
            size_t o = (size_t)n * C + j0;
            y1[o]      = p1[i][0] + blj0;
            y1[o + 64] = p1[i][1] + blj1;
            y2[o]      = p2[i][0] + blj0;
            y2[o + 64] = p2[i][1] + blj1;
        }
    }
}

// ---------------- attention pooling ----------------
__global__ __launch_bounds__(256) void attention(
    const float* x1, const float* x2, const float* x3, const float* x4,
    const float* __restrict__ W1, const float* __restrict__ b1, const float* __restrict__ W2,
    float* emb) {
    __shared__ __align__(16) float sW1[128 * 64];
    __shared__ float sb1[64];
    __shared__ float sW2[64];
    {
        const float4* g = (const float4*)W1;
        float4* s = (float4*)sW1;
        for (int idx = threadIdx.x; idx < 2048; idx += 256) s[idx] = g[idx];
        if (threadIdx.x < 64) {
            sb1[threadIdx.x] = b1[threadIdx.x];
            sW2[threadIdx.x] = W2[threadIdx.x];
        }
    }
    __syncthreads();
    int node = blockIdx.x * 4 + (threadIdx.x >> 6);
    int lane = threadIdx.x & 63;
    const float* zs[4] = {x1 + (size_t)node * C, x2 + (size_t)node * C,
                          x3 + (size_t)node * C, x4 + (size_t)node * C};
    float w[4];
#pragma unroll
    for (int br = 0; br < 4; ++br) {
        float hj = sb1[lane];
        for (int k = 0; k < 128; k += 4) {
            float4 z4 = *(const float4*)(zs[br] + k);
            hj += z4.x * sW1[(k + 0) * 64 + lane] + z4.y * sW1[(k + 1) * 64 + lane]
                + z4.z * sW1[(k + 2) * 64 + lane] + z4.w * sW1[(k + 3) * 64 + lane];
        }
        float cl = fminf(fmaxf(hj, -15.f), 15.f);
        float e2 = __expf(2.f * cl);
        float th = (e2 - 1.f) / (e2 + 1.f);
        w[br] = wave_sum(th * sW2[lane]);
    }
    float m = fmaxf(fmaxf(w[0], w[1]), fmaxf(w[2], w[3]));
    float e0 = __expf(w[0] - m), e1 = __expf(w[1] - m);
    float e2b = __expf(w[2] - m), e3 = __expf(w[3] - m);
    float inv = 1.f / (e0 + e1 + e2b + e3);
    float b0 = e0 * inv, bb1 = e1 * inv, b2 = e2b * inv, b3 = e3 * inv;
#pragma unroll
    for (int part = 0; part < 2; ++part) {
        int ch = lane + part * 64;
        float v = b0 * zs[0][ch] + bb1 * zs[1][ch] + b2 * zs[2][ch] + b3 * zs[3][ch];
        emb[(size_t)node * C + ch] = v;
    }
}

extern "C" void kernel_launch(void* const* d_in, const int* in_sizes, int n_in,
                              void* d_out, int out_size, void* d_ws, size_t ws_size,
                              hipStream_t stream) {
    const float* x   = (const float*)d_in[0];
    const int* row   = (const int*)d_in[1];
    const int* col   = (const int*)d_in[2];
    const float* Wl0 = (const float*)d_in[3];
    const float* bl0 = (const float*)d_in[4];
    const float* Wr0 = (const float*)d_in[5];
    const float* Wl1 = (const float*)d_in[6];
    const float* bl1 = (const float*)d_in[7];
    const float* Wr1 = (const float*)d_in[8];
    const float* aW1 = (const float*)d_in[9];
    const float* ab1 = (const float*)d_in[10];
    const float* aW2 = (const float*)d_in[11];

    float* out = (float*)d_out;
    float* emb = out;                         // also x1 scratch (written last, per-node disjoint)
    float* x3  = out + (size_t)NN * C;
    float* x4  = out + 2 * (size_t)NN * C;

    char* ws = (char*)d_ws;
    size_t off = 0;
    auto alloc = [&](size_t bytes) -> void* {
        void* p = ws + off;
        off += (bytes + 255) & ~(size_t)255;
        return p;
    };
    int* deg     = (int*)alloc((size_t)NN * 4);
    int* offsets = (int*)alloc((size_t)(NN + 1) * 4);
    int* cursor  = (int*)alloc((size_t)NN * 4);
    int* perm    = (int*)alloc((size_t)NE * 4);
    float* n2    = (float*)alloc((size_t)NN * 4);
    float* n2b   = (float*)alloc((size_t)NN * 4);
    float* bufA  = (float*)alloc((size_t)NN * C * 4);   // aggc -> agg1
    float* bufB  = (float*)alloc((size_t)NN * C * 4);   // agge -> agg2
    float* bufC  = (float*)alloc((size_t)NN * C * 4);   // x2

    hipMemsetAsync(deg, 0, (size_t)NN * 4, stream);
    count_deg<<<(NE + 255) / 256, 256, 0, stream>>>(row, deg);
    scan_deg<<<1, 1024, 0, stream>>>(deg, offsets, cursor);
    bucket_edges<<<(NE + 255) / 256, 256, 0, stream>>>(row, cursor, perm);

    norm2_kernel<<<NN / 4, 256, 0, stream>>>(x, n2);
    l1_agg<<<NN / 4, 256, 0, stream>>>(x, col, perm, offsets, n2, bufA, bufB);
    gemm1<<<(NN + 31) / 32, 256, 0, stream>>>(bufA, bufB, x, Wl0, Wr0, bl0, x3, x4);

    norm2_kernel<<<NN / 4, 256, 0, stream>>>(x3, n2b);
    l2_agg<<<NN / 4, 256, 0, stream>>>(x3, x4, col, perm, offsets, n2b, bufA, bufB);
    gemm2<<<(NN + 31) / 32, 256, 0, stream>>>(bufA, bufB, x3, x4, Wl1, Wr1, bl1, emb /*x1*/, bufC /*x2*/);

    attention<<<NN / 4, 256, 0, stream>>>(emb /*x1*/, bufC /*x2*/, x3, x4, aW1, ab1, aW2, out);
}

// Round 3
// 1045.953 us; speedup vs baseline: 1.7387x; 1.3722x over previous
//
#include <hip/hip_runtime.h>

#define NN 50000
#define NE 800000
#define C 128

typedef __attribute__((ext_vector_type(8))) short short8_t;
typedef __attribute__((ext_vector_type(4))) float f32x4;

__device__ __forceinline__ float wave_sum(float v) {
#pragma unroll
    for (int off = 32; off > 0; off >>= 1) v += __shfl_xor(v, off, 64);
    return v;
}

__device__ __forceinline__ unsigned short f2bf(float f) {
    union { float f; unsigned u; } v; v.f = f;
    unsigned r = v.u + 0x7fffu + ((v.u >> 16) & 1u);   // RNE
    return (unsigned short)(r >> 16);
}

// ---------------- CSR build ----------------
__global__ void count_deg(const int* __restrict__ row, int* __restrict__ deg) {
    int e = blockIdx.x * blockDim.x + threadIdx.x;
    if (e < NE) atomicAdd(&deg[row[e]], 1);
}

__global__ void scan_deg(const int* __restrict__ deg, int* __restrict__ offsets,
                         int* __restrict__ cursor) {
    __shared__ int part[1024];
    int t = threadIdx.x;
    const int CHUNK = (NN + 1023) / 1024;
    int base = t * CHUNK;
    int s = 0;
    for (int i = 0; i < CHUNK; ++i) {
        int idx = base + i;
        if (idx < NN) s += deg[idx];
    }
    part[t] = s;
    __syncthreads();
    for (int off = 1; off < 1024; off <<= 1) {
        int v = part[t];
        int add = (t >= off) ? part[t - off] : 0;
        __syncthreads();
        part[t] = v + add;
        __syncthreads();
    }
    int run = (t == 0) ? 0 : part[t - 1];
    for (int i = 0; i < CHUNK; ++i) {
        int idx = base + i;
        if (idx < NN) {
            offsets[idx] = run;
            cursor[idx] = run;
            run += deg[idx];
        }
    }
    if (t == 1023) offsets[NN] = part[1023];
}

__global__ void bucket_edges(const int* __restrict__ row, int* __restrict__ cursor,
                             int* __restrict__ perm) {
    int e = blockIdx.x * blockDim.x + threadIdx.x;
    if (e < NE) {
        int p = atomicAdd(&cursor[row[e]], 1);
        perm[p] = e;
    }
}

// ---------------- per-node squared norms ----------------
__global__ void norm2_kernel(const float* __restrict__ x, float* __restrict__ out) {
    int node = blockIdx.x * 4 + (threadIdx.x >> 6);
    int lane = threadIdx.x & 63;
    const float2 v = *(const float2*)(x + (size_t)node * C + lane * 2);
    float s = wave_sum(v.x * v.x + v.y * v.y);
    if (lane == 0) out[node] = s;
}

// ---------------- cast x -> bf16 ----------------
__global__ void cast_x(const float* __restrict__ x, unsigned short* __restrict__ xbf) {
    int i = blockIdx.x * 256 + threadIdx.x;   // 4 elems each
    float4 v = ((const float4*)x)[i];
    ushort2 a; a.x = f2bf(v.x); a.y = f2bf(v.y);
    ushort2 b; b.x = f2bf(v.z); b.y = f2bf(v.w);
    ((ushort2*)xbf)[i * 2] = a;
    ((ushort2*)xbf)[i * 2 + 1] = b;
}

// ---------------- weight prep: Bt[layer][chunk][n][kk] = W[kk][n] bf16 ----------------
__global__ void prep_w(const float* __restrict__ Wl0, const float* __restrict__ Wr0,
                       const float* __restrict__ Wl1, const float* __restrict__ Wr1,
                       unsigned short* __restrict__ Bt) {
    int id = blockIdx.x * 256 + threadIdx.x;   // [0, 65536)
    int layer = id >> 15;
    int c = (id >> 14) & 1;
    int n = (id >> 7) & 127;
    int kk = id & 127;
    const float* W = layer == 0 ? (c == 0 ? Wl0 : Wr0) : (c == 0 ? Wl1 : Wr1);
    Bt[id] = f2bf(W[kk * 128 + n]);
}

// ---------------- layer-1 fused similarity + aggregation (bf16 out) ----------------
__global__ void l1_agg(const float* __restrict__ x, const int* __restrict__ col,
                       const int* __restrict__ perm, const int* __restrict__ offsets,
                       const float* __restrict__ n2, unsigned short* __restrict__ aggc,
                       unsigned short* __restrict__ agge) {
    int node = blockIdx.x * 4 + (threadIdx.x >> 6);
    int lane = threadIdx.x & 63;
    const float2 xa = *(const float2*)(x + (size_t)node * C + lane * 2);
    float na2 = n2[node];
    int beg = offsets[node], end = offsets[node + 1];
    float ac0 = 0.f, ac1 = 0.f, ae0 = 0.f, ae1 = 0.f;
    for (int p = beg; p < end; ++p) {
        int c = col[perm[p]];
        const float2 xb = *(const float2*)(x + (size_t)c * C + lane * 2);
        float dp = xa.x * xb.x + xa.y * xb.y;
        float d0 = xa.x - xb.x + 1e-6f;
        float d1 = xa.y - xb.y + 1e-6f;
        float ep = d0 * d0 + d1 * d1;
#pragma unroll
        for (int off = 32; off > 0; off >>= 1) {
            dp += __shfl_xor(dp, off, 64);
            ep += __shfl_xor(ep, off, 64);
        }
        float wc = dp / fmaxf(sqrtf(na2 * n2[c]), 1e-8f);
        float we = sqrtf(ep);
        ac0 += wc * xb.x; ac1 += wc * xb.y;
        ae0 += we * xb.x; ae1 += we * xb.y;
    }
    float inv = 1.f / fmaxf((float)(end - beg), 1.f);
    ushort2 uc; uc.x = f2bf(ac0 * inv); uc.y = f2bf(ac1 * inv);
    ushort2 ue; ue.x = f2bf(ae0 * inv); ue.y = f2bf(ae1 * inv);
    *(ushort2*)(aggc + (size_t)node * C + lane * 2) = uc;
    *(ushort2*)(agge + (size_t)node * C + lane * 2) = ue;
}

// ---------------- layer-2 fused similarity + aggregation (bf16 out) ----------------
__global__ void l2_agg(const float* __restrict__ x3, const float* __restrict__ x4,
                       const int* __restrict__ col, const int* __restrict__ perm,
                       const int* __restrict__ offsets, const float* __restrict__ n2_3,
                       unsigned short* __restrict__ agg1, unsigned short* __restrict__ agg2) {
    int node = blockIdx.x * 4 + (threadIdx.x >> 6);
    int lane = threadIdx.x & 63;
    const float2 a3 = *(const float2*)(x3 + (size_t)node * C + lane * 2);
    const float2 a4 = *(const float2*)(x4 + (size_t)node * C + lane * 2);
    float na2 = n2_3[node];
    int beg = offsets[node], end = offsets[node + 1];
    float p10 = 0.f, p11 = 0.f, p20 = 0.f, p21 = 0.f;
    for (int p = beg; p < end; ++p) {
        int c = col[perm[p]];
        const float2 b3 = *(const float2*)(x3 + (size_t)c * C + lane * 2);
        const float2 b4 = *(const float2*)(x4 + (size_t)c * C + lane * 2);
        float dp = a3.x * b3.x + a3.y * b3.y;
        float d0 = a4.x - b4.x + 1e-6f;
        float d1 = a4.y - b4.y + 1e-6f;
        float ep = d0 * d0 + d1 * d1;
#pragma unroll
        for (int off = 32; off > 0; off >>= 1) {
            dp += __shfl_xor(dp, off, 64);
            ep += __shfl_xor(ep, off, 64);
        }
        float wc = dp / fmaxf(sqrtf(na2 * n2_3[c]), 1e-8f);
        float we = sqrtf(ep);
        p10 += wc * b3.x; p11 += wc * b3.y;
        p20 += we * b4.x; p21 += we * b4.y;
    }
    float inv = 1.f / fmaxf((float)(end - beg), 1.f);
    ushort2 u1; u1.x = f2bf(p10 * inv); u1.y = f2bf(p11 * inv);
    ushort2 u2; u2.x = f2bf(p20 * inv); u2.y = f2bf(p21 * inv);
    *(ushort2*)(agg1 + (size_t)node * C + lane * 2) = u1;
    *(ushort2*)(agg2 + (size_t)node * C + lane * 2) = u2;
}

// ---------------- MFMA GEMM: C[n,128] = [A0|A1](n, 256) @ B(256,128) + bias ----------------
// A0/A1: bf16 [NN][128] (K-chunks 0 and 1). Bt: bf16 [2][128n][128k] pre-transposed.
// 128x128 C-tile per block; 4 waves, each 64x64 via 16x16x32 MFMA.
__global__ __launch_bounds__(256) void gemm_mfma(
    const unsigned short* __restrict__ A0, const unsigned short* __restrict__ A1,
    const unsigned short* __restrict__ Bt, const float* __restrict__ bias,
    float* __restrict__ Cout, unsigned short* __restrict__ Cbf, int relu) {
    __shared__ __align__(16) unsigned short sA[128 * 136];  // +8 pad: 272B row stride
    __shared__ __align__(16) unsigned short sB[128 * 136];
    const int tx = threadIdx.x;
    const int l = tx & 63;
    const int wv = tx >> 6;
    const int wm = wv >> 1, wn = wv & 1;
    const int lr = l & 15;
    const int lq = l >> 4;
    const int n0 = blockIdx.x * 128;

    f32x4 acc[4][4] = {};
    for (int c = 0; c < 2; ++c) {
        const unsigned short* Ac = (c == 0) ? A0 : A1;
#pragma unroll
        for (int it = 0; it < 8; ++it) {
            int idx = it * 256 + tx;        // 0..2047: 16B slot id
            int r = idx >> 4, s = idx & 15;
            int n = n0 + r; n = n < NN ? n : NN - 1;
            *(short8_t*)(sA + r * 136 + s * 8) = *(const short8_t*)(Ac + (size_t)n * 128 + s * 8);
            *(short8_t*)(sB + r * 136 + s * 8) = *(const short8_t*)(Bt + c * 16384 + idx * 8);
        }
        __syncthreads();
#pragma unroll
        for (int ks = 0; ks < 4; ++ks) {
            short8_t af[4], bfr[4];
#pragma unroll
            for (int t = 0; t < 4; ++t) {
                af[t]  = *(const short8_t*)(sA + (wm * 64 + t * 16 + lr) * 136 + ks * 32 + lq * 8);
                bfr[t] = *(const short8_t*)(sB + (wn * 64 + t * 16 + lr) * 136 + ks * 32 + lq * 8);
            }
#pragma unroll
            for (int mt = 0; mt < 4; ++mt)
#pragma unroll
                for (int nt = 0; nt < 4; ++nt)
                    acc[mt][nt] = __builtin_amdgcn_mfma_f32_16x16x32_bf16(af[mt], bfr[nt], acc[mt][nt], 0, 0, 0);
        }
        __syncthreads();
    }
#pragma unroll
    for (int mt = 0; mt < 4; ++mt) {
        int rbase = wm * 64 + mt * 16 + lq * 4;
#pragma unroll
        for (int nt = 0; nt < 4; ++nt) {
            int col = wn * 64 + nt * 16 + lr;
            float bv = bias[col];
#pragma unroll
            for (int rg = 0; rg < 4; ++rg) {
                int n = n0 + rbase + rg;
                if (n < NN) {
                    float y = acc[mt][nt][rg] + bv;
                    if (relu) y = fmaxf(y, 0.f);
                    Cout[(size_t)n * 128 + col] = y;
                    if (Cbf) Cbf[(size_t)n * 128 + col] = f2bf(y);
                }
            }
        }
    }
}

// ---------------- attention pooling ----------------
__global__ __launch_bounds__(256) void attention(
    const float* x1, const float* x2, const float* x3, const float* x4,
    const float* __restrict__ W1, const float* __restrict__ b1, const float* __restrict__ W2,
    float* emb) {
    __shared__ __align__(16) float sW1[128 * 64];
    __shared__ float sb1[64];
    __shared__ float sW2[64];
    {
        const float4* g = (const float4*)W1;
        float4* s = (float4*)sW1;
        for (int idx = threadIdx.x; idx < 2048; idx += 256) s[idx] = g[idx];
        if (threadIdx.x < 64) {
            sb1[threadIdx.x] = b1[threadIdx.x];
            sW2[threadIdx.x] = W2[threadIdx.x];
        }
    }
    __syncthreads();
    int node = blockIdx.x * 4 + (threadIdx.x >> 6);
    int lane = threadIdx.x & 63;
    const float* zs[4] = {x1 + (size_t)node * C, x2 + (size_t)node * C,
                          x3 + (size_t)node * C, x4 + (size_t)node * C};
    float w[4];
#pragma unroll
    for (int br = 0; br < 4; ++br) {
        float hj = sb1[lane];
        for (int k = 0; k < 128; k += 4) {
            float4 z4 = *(const float4*)(zs[br] + k);
            hj += z4.x * sW1[(k + 0) * 64 + lane] + z4.y * sW1[(k + 1) * 64 + lane]
                + z4.z * sW1[(k + 2) * 64 + lane] + z4.w * sW1[(k + 3) * 64 + lane];
        }
        float cl = fminf(fmaxf(hj, -15.f), 15.f);
        float e2 = __expf(2.f * cl);
        float th = (e2 - 1.f) / (e2 + 1.f);
        w[br] = wave_sum(th * sW2[lane]);
    }
    float m = fmaxf(fmaxf(w[0], w[1]), fmaxf(w[2], w[3]));
    float e0 = __expf(w[0] - m), e1 = __expf(w[1] - m);
    float e2b = __expf(w[2] - m), e3 = __expf(w[3] - m);
    float inv = 1.f / (e0 + e1 + e2b + e3);
    float b0 = e0 * inv, bb1 = e1 * inv, b2 = e2b * inv, b3 = e3 * inv;
#pragma unroll
    for (int part = 0; part < 2; ++part) {
        int ch = lane + part * 64;
        float v = b0 * zs[0][ch] + bb1 * zs[1][ch] + b2 * zs[2][ch] + b3 * zs[3][ch];
        emb[(size_t)node * C + ch] = v;
    }
}

extern "C" void kernel_launch(void* const* d_in, const int* in_sizes, int n_in,
                              void* d_out, int out_size, void* d_ws, size_t ws_size,
                              hipStream_t stream) {
    const float* x   = (const float*)d_in[0];
    const int* row   = (const int*)d_in[1];
    const int* col   = (const int*)d_in[2];
    const float* Wl0 = (const float*)d_in[3];
    const float* bl0 = (const float*)d_in[4];
    const float* Wr0 = (const float*)d_in[5];
    const float* Wl1 = (const float*)d_in[6];
    const float* bl1 = (const float*)d_in[7];
    const float* Wr1 = (const float*)d_in[8];
    const float* aW1 = (const float*)d_in[9];
    const float* ab1 = (const float*)d_in[10];
    const float* aW2 = (const float*)d_in[11];

    float* out = (float*)d_out;
    float* emb = out;                         // also x1 (written by gemm2 b0, finalized by attention)
    float* x3  = out + (size_t)NN * C;
    float* x4  = out + 2 * (size_t)NN * C;

    char* ws = (char*)d_ws;
    size_t off = 0;
    auto alloc = [&](size_t bytes) -> void* {
        void* p = ws + off;
        off += (bytes + 255) & ~(size_t)255;
        return p;
    };
    int* deg     = (int*)alloc((size_t)NN * 4);
    int* offsets = (int*)alloc((size_t)(NN + 1) * 4);
    int* cursor  = (int*)alloc((size_t)NN * 4);
    int* perm    = (int*)alloc((size_t)NE * 4);
    float* n2    = (float*)alloc((size_t)NN * 4);
    float* n2b   = (float*)alloc((size_t)NN * 4);
    unsigned short* xbf   = (unsigned short*)alloc((size_t)NN * C * 2);
    unsigned short* aggcb = (unsigned short*)alloc((size_t)NN * C * 2);  // reused: agg1
    unsigned short* aggeb = (unsigned short*)alloc((size_t)NN * C * 2);  // reused: agg2
    unsigned short* x3b   = (unsigned short*)alloc((size_t)NN * C * 2);
    unsigned short* x4b   = (unsigned short*)alloc((size_t)NN * C * 2);
    unsigned short* Bt    = (unsigned short*)alloc((size_t)65536 * 2);
    float* x2f   = (float*)alloc((size_t)NN * C * 4);

    hipMemsetAsync(deg, 0, (size_t)NN * 4, stream);
    count_deg<<<(NE + 255) / 256, 256, 0, stream>>>(row, deg);
    scan_deg<<<1, 1024, 0, stream>>>(deg, offsets, cursor);
    bucket_edges<<<(NE + 255) / 256, 256, 0, stream>>>(row, cursor, perm);

    cast_x<<<(NN * C / 4 + 255) / 256, 256, 0, stream>>>(x, xbf);
    prep_w<<<256, 256, 0, stream>>>(Wl0, Wr0, Wl1, Wr1, Bt);

    norm2_kernel<<<NN / 4, 256, 0, stream>>>(x, n2);
    l1_agg<<<NN / 4, 256, 0, stream>>>(x, col, perm, offsets, n2, aggcb, aggeb);

    const int GB = (NN + 127) / 128;
    gemm_mfma<<<GB, 256, 0, stream>>>(aggcb, xbf, Bt, bl0, x3, x3b, 1);
    gemm_mfma<<<GB, 256, 0, stream>>>(aggeb, xbf, Bt, bl0, x4, x4b, 1);

    norm2_kernel<<<NN / 4, 256, 0, stream>>>(x3, n2b);
    l2_agg<<<NN / 4, 256, 0, stream>>>(x3, x4, col, perm, offsets, n2b, aggcb, aggeb);

    gemm_mfma<<<GB, 256, 0, stream>>>(aggcb, x3b, Bt + 32768, bl1, emb, nullptr, 0);
    gemm_mfma<<<GB, 256, 0, stream>>>(aggeb, x4b, Bt + 32768, bl1, x2f, nullptr, 0);

    attention<<<NN / 4, 256, 0, stream>>>(emb, x2f, x3, x4, aW1, ab1, aW2, out);
}

// Round 4
// 742.498 us; speedup vs baseline: 2.4493x; 1.4087x over previous
//
#include <hip/hip_runtime.h>

#define NN 50000
#define NE 800000
#define C 128

typedef __attribute__((ext_vector_type(8))) short short8_t;
typedef __attribute__((ext_vector_type(4))) float f32x4;

__device__ __forceinline__ float wave_sum(float v) {
#pragma unroll
    for (int off = 32; off > 0; off >>= 1) v += __shfl_xor(v, off, 64);
    return v;
}

__device__ __forceinline__ unsigned short f2bf(float f) {
    union { float f; unsigned u; } v; v.f = f;
    unsigned r = v.u + 0x7fffu + ((v.u >> 16) & 1u);   // RNE
    return (unsigned short)(r >> 16);
}

// ---------------- CSR build ----------------
__global__ void count_deg(const int* __restrict__ row, int* __restrict__ deg) {
    int e = blockIdx.x * blockDim.x + threadIdx.x;
    if (e < NE) atomicAdd(&deg[row[e]], 1);
}

// 3-phase parallel exclusive scan of deg[NN] (49 blocks x 1024 elems)
#define SCAN_NB ((NN + 1023) / 1024)

__global__ void deg_block_sums(const int* __restrict__ deg, int* __restrict__ bsum) {
    __shared__ int sred[256];
    int t = threadIdx.x;
    int base = blockIdx.x * 1024 + t * 4;
    int s = 0;
    if (base + 3 < NN) {
        int4 v = *(const int4*)(deg + base);
        s = v.x + v.y + v.z + v.w;
    } else {
        for (int i = 0; i < 4; ++i) if (base + i < NN) s += deg[base + i];
    }
    sred[t] = s; __syncthreads();
    for (int off = 128; off > 0; off >>= 1) {
        if (t < off) sred[t] += sred[t + off];
        __syncthreads();
    }
    if (t == 0) bsum[blockIdx.x] = sred[0];
}

__global__ void scan_bsums(int* __restrict__ bsum) {   // 1 block x 64, SCAN_NB <= 64
    int t = threadIdx.x;
    int v = (t < SCAN_NB) ? bsum[t] : 0;
#pragma unroll
    for (int off = 1; off < 64; off <<= 1) {
        int u = __shfl_up(v, off, 64);
        if (t >= off) v += u;
    }
    int ex = __shfl_up(v, 1, 64);
    if (t == 0) ex = 0;
    if (t < SCAN_NB) bsum[t] = ex;
}

__global__ void scan_within(const int* __restrict__ deg, const int* __restrict__ bsum,
                            int* __restrict__ offsets, int* __restrict__ cursor) {
    __shared__ int sdat[256];
    int t = threadIdx.x;
    int base = blockIdx.x * 1024 + t * 4;
    int d[4] = {0, 0, 0, 0};
    if (base + 3 < NN) {
        int4 v = *(const int4*)(deg + base);
        d[0] = v.x; d[1] = v.y; d[2] = v.z; d[3] = v.w;
    } else {
        for (int i = 0; i < 4; ++i) if (base + i < NN) d[i] = deg[base + i];
    }
    sdat[t] = d[0] + d[1] + d[2] + d[3];
    __syncthreads();
    for (int off = 1; off < 256; off <<= 1) {
        int v = sdat[t];
        int add = (t >= off) ? sdat[t - off] : 0;
        __syncthreads();
        sdat[t] = v + add;
        __syncthreads();
    }
    int run = bsum[blockIdx.x] + ((t == 0) ? 0 : sdat[t - 1]);
    for (int i = 0; i < 4; ++i) {
        int idx = base + i;
        if (idx < NN) { offsets[idx] = run; cursor[idx] = run; run += d[i]; }
    }
    if (blockIdx.x == 0 && t == 0) offsets[NN] = NE;
}

// bucket: store col VALUE at CSR slot (kills the perm indirection)
__global__ void bucket_edges(const int* __restrict__ row, const int* __restrict__ col,
                             int* __restrict__ cursor, int* __restrict__ colv) {
    int e = blockIdx.x * blockDim.x + threadIdx.x;
    if (e < NE) {
        int p = atomicAdd(&cursor[row[e]], 1);
        colv[p] = col[e];
    }
}

// ---------------- per-node squared norms ----------------
__global__ void norm2_kernel(const float* __restrict__ x, float* __restrict__ out) {
    int node = blockIdx.x * 4 + (threadIdx.x >> 6);
    int lane = threadIdx.x & 63;
    const float2 v = *(const float2*)(x + (size_t)node * C + lane * 2);
    float s = wave_sum(v.x * v.x + v.y * v.y);
    if (lane == 0) out[node] = s;
}

// ---------------- cast x -> bf16 ----------------
__global__ void cast_x(const float* __restrict__ x, unsigned short* __restrict__ xbf) {
    int i = blockIdx.x * 256 + threadIdx.x;   // 4 elems each
    float4 v = ((const float4*)x)[i];
    ushort2 a; a.x = f2bf(v.x); a.y = f2bf(v.y);
    ushort2 b; b.x = f2bf(v.z); b.y = f2bf(v.w);
    ((ushort2*)xbf)[i * 2] = a;
    ((ushort2*)xbf)[i * 2 + 1] = b;
}

// ---------------- weight prep: Bt[layer][chunk][n][kk] = W[kk][n] bf16 ----------------
__global__ void prep_w(const float* __restrict__ Wl0, const float* __restrict__ Wr0,
                       const float* __restrict__ Wl1, const float* __restrict__ Wr1,
                       unsigned short* __restrict__ Bt) {
    int id = blockIdx.x * 256 + threadIdx.x;   // [0, 65536)
    int layer = id >> 15;
    int c = (id >> 14) & 1;
    int n = (id >> 7) & 127;
    int kk = id & 127;
    const float* W = layer == 0 ? (c == 0 ? Wl0 : Wr0) : (c == 0 ? Wl1 : Wr1);
    Bt[id] = f2bf(W[kk * 128 + n]);
}

// ---------------- layer-1 fused similarity + aggregation (bf16 out, prefetch) ----------------
__global__ void l1_agg(const float* __restrict__ x, const int* __restrict__ colv,
                       const int* __restrict__ offsets, const float* __restrict__ n2,
                       unsigned short* __restrict__ aggc, unsigned short* __restrict__ agge) {
    int node = blockIdx.x * 4 + (threadIdx.x >> 6);
    int lane = threadIdx.x & 63;
    const float2 xa = *(const float2*)(x + (size_t)node * C + lane * 2);
    float na2 = n2[node];
    int beg = offsets[node], end = offsets[node + 1];
    float ac0 = 0.f, ac1 = 0.f, ae0 = 0.f, ae1 = 0.f;
    float2 xbN = make_float2(0.f, 0.f);
    float nN = 0.f;
    if (beg < end) {
        int c0 = colv[beg];
        xbN = *(const float2*)(x + (size_t)c0 * C + lane * 2);
        nN = n2[c0];
    }
    for (int p = beg; p < end; ++p) {
        float2 xb = xbN;
        float nc = nN;
        if (p + 1 < end) {
            int c2 = colv[p + 1];
            xbN = *(const float2*)(x + (size_t)c2 * C + lane * 2);
            nN = n2[c2];
        }
        float dp = xa.x * xb.x + xa.y * xb.y;
        float d0 = xa.x - xb.x + 1e-6f;
        float d1 = xa.y - xb.y + 1e-6f;
        float ep = d0 * d0 + d1 * d1;
#pragma unroll
        for (int off = 32; off > 0; off >>= 1) {
            dp += __shfl_xor(dp, off, 64);
            ep += __shfl_xor(ep, off, 64);
        }
        float wc = dp / fmaxf(sqrtf(na2 * nc), 1e-8f);
        float we = sqrtf(ep);
        ac0 += wc * xb.x; ac1 += wc * xb.y;
        ae0 += we * xb.x; ae1 += we * xb.y;
    }
    float inv = 1.f / fmaxf((float)(end - beg), 1.f);
    ushort2 uc; uc.x = f2bf(ac0 * inv); uc.y = f2bf(ac1 * inv);
    ushort2 ue; ue.x = f2bf(ae0 * inv); ue.y = f2bf(ae1 * inv);
    *(ushort2*)(aggc + (size_t)node * C + lane * 2) = uc;
    *(ushort2*)(agge + (size_t)node * C + lane * 2) = ue;
}

// ---------------- layer-2 fused similarity + aggregation (bf16 out, prefetch) ----------------
__global__ void l2_agg(const float* __restrict__ x3, const float* __restrict__ x4,
                       const int* __restrict__ colv, const int* __restrict__ offsets,
                       const float* __restrict__ n2_3,
                       unsigned short* __restrict__ agg1, unsigned short* __restrict__ agg2) {
    int node = blockIdx.x * 4 + (threadIdx.x >> 6);
    int lane = threadIdx.x & 63;
    const float2 a3 = *(const float2*)(x3 + (size_t)node * C + lane * 2);
    const float2 a4 = *(const float2*)(x4 + (size_t)node * C + lane * 2);
    float na2 = n2_3[node];
    int beg = offsets[node], end = offsets[node + 1];
    float p10 = 0.f, p11 = 0.f, p20 = 0.f, p21 = 0.f;
    float2 b3N = make_float2(0.f, 0.f), b4N = make_float2(0.f, 0.f);
    float nN = 0.f;
    if (beg < end) {
        int c0 = colv[beg];
        b3N = *(const float2*)(x3 + (size_t)c0 * C + lane * 2);
        b4N = *(const float2*)(x4 + (size_t)c0 * C + lane * 2);
        nN = n2_3[c0];
    }
    for (int p = beg; p < end; ++p) {
        float2 b3 = b3N, b4 = b4N;
        float nc = nN;
        if (p + 1 < end) {
            int c2 = colv[p + 1];
            b3N = *(const float2*)(x3 + (size_t)c2 * C + lane * 2);
            b4N = *(const float2*)(x4 + (size_t)c2 * C + lane * 2);
            nN = n2_3[c2];
        }
        float dp = a3.x * b3.x + a3.y * b3.y;
        float d0 = a4.x - b4.x + 1e-6f;
        float d1 = a4.y - b4.y + 1e-6f;
        float ep = d0 * d0 + d1 * d1;
#pragma unroll
        for (int off = 32; off > 0; off >>= 1) {
            dp += __shfl_xor(dp, off, 64);
            ep += __shfl_xor(ep, off, 64);
        }
        float wc = dp / fmaxf(sqrtf(na2 * nc), 1e-8f);
        float we = sqrtf(ep);
        p10 += wc * b3.x; p11 += wc * b3.y;
        p20 += we * b4.x; p21 += we * b4.y;
    }
    float inv = 1.f / fmaxf((float)(end - beg), 1.f);
    ushort2 u1; u1.x = f2bf(p10 * inv); u1.y = f2bf(p11 * inv);
    ushort2 u2; u2.x = f2bf(p20 * inv); u2.y = f2bf(p21 * inv);
    *(ushort2*)(agg1 + (size_t)node * C + lane * 2) = u1;
    *(ushort2*)(agg2 + (size_t)node * C + lane * 2) = u2;
}

// ---------------- MFMA GEMM: C[n,128] = [A0|A1](n, 256) @ B(256,128) + bias ----------------
__global__ __launch_bounds__(256) void gemm_mfma(
    const unsigned short* __restrict__ A0, const unsigned short* __restrict__ A1,
    const unsigned short* __restrict__ Bt, const float* __restrict__ bias,
    float* __restrict__ Cout, unsigned short* __restrict__ Cbf, int relu) {
    __shared__ __align__(16) unsigned short sA[128 * 136];  // +8 pad: 272B row stride
    __shared__ __align__(16) unsigned short sB[128 * 136];
    const int tx = threadIdx.x;
    const int l = tx & 63;
    const int wv = tx >> 6;
    const int wm = wv >> 1, wn = wv & 1;
    const int lr = l & 15;
    const int lq = l >> 4;
    const int n0 = blockIdx.x * 128;

    f32x4 acc[4][4] = {};
    for (int c = 0; c < 2; ++c) {
        const unsigned short* Ac = (c == 0) ? A0 : A1;
#pragma unroll
        for (int it = 0; it < 8; ++it) {
            int idx = it * 256 + tx;        // 0..2047: 16B slot id
            int r = idx >> 4, s = idx & 15;
            int n = n0 + r; n = n < NN ? n : NN - 1;
            *(short8_t*)(sA + r * 136 + s * 8) = *(const short8_t*)(Ac + (size_t)n * 128 + s * 8);
            *(short8_t*)(sB + r * 136 + s * 8) = *(const short8_t*)(Bt + c * 16384 + idx * 8);
        }
        __syncthreads();
#pragma unroll
        for (int ks = 0; ks < 4; ++ks) {
            short8_t af[4], bfr[4];
#pragma unroll
            for (int t = 0; t < 4; ++t) {
                af[t]  = *(const short8_t*)(sA + (wm * 64 + t * 16 + lr) * 136 + ks * 32 + lq * 8);
                bfr[t] = *(const short8_t*)(sB + (wn * 64 + t * 16 + lr) * 136 + ks * 32 + lq * 8);
            }
#pragma unroll
            for (int mt = 0; mt < 4; ++mt)
#pragma unroll
                for (int nt = 0; nt < 4; ++nt)
                    acc[mt][nt] = __builtin_amdgcn_mfma_f32_16x16x32_bf16(af[mt], bfr[nt], acc[mt][nt], 0, 0, 0);
        }
        __syncthreads();
    }
#pragma unroll
    for (int mt = 0; mt < 4; ++mt) {
        int rbase = wm * 64 + mt * 16 + lq * 4;
#pragma unroll
        for (int nt = 0; nt < 4; ++nt) {
            int col = wn * 64 + nt * 16 + lr;
            float bv = bias[col];
#pragma unroll
            for (int rg = 0; rg < 4; ++rg) {
                int n = n0 + rbase + rg;
                if (n < NN) {
                    float y = acc[mt][nt][rg] + bv;
                    if (relu) y = fmaxf(y, 0.f);
                    Cout[(size_t)n * 128 + col] = y;
                    if (Cbf) Cbf[(size_t)n * 128 + col] = f2bf(y);
                }
            }
        }
    }
}

// ---------------- attention pooling: W1 col in registers, grid-stride, 4 indep chains ----------------
__global__ __launch_bounds__(256) void attention(
    const float* __restrict__ x1, const float* __restrict__ x2,
    const float* __restrict__ x3, const float* __restrict__ x4,
    const float* __restrict__ W1, const float* __restrict__ b1, const float* __restrict__ W2,
    float* __restrict__ emb) {
    int w = threadIdx.x >> 6, lane = threadIdx.x & 63;
    float rw1[128];
#pragma unroll
    for (int k = 0; k < 128; ++k) rw1[k] = W1[k * 64 + lane];   // coalesced across lanes
    float biasj = b1[lane], w2j = W2[lane];

    for (int node = blockIdx.x * 4 + w; node < NN; node += gridDim.x * 4) {
        const float* zp[4] = {x1 + (size_t)node * C, x2 + (size_t)node * C,
                              x3 + (size_t)node * C, x4 + (size_t)node * C};
        float wsc[4];
#pragma unroll
        for (int br = 0; br < 4; ++br) {
            float a0 = 0.f, a1 = 0.f, a2 = 0.f, a3 = 0.f;
#pragma unroll
            for (int k = 0; k < 128; k += 16) {
                float4 z0 = *(const float4*)(zp[br] + k);
                float4 z1 = *(const float4*)(zp[br] + k + 4);
                float4 z2 = *(const float4*)(zp[br] + k + 8);
                float4 z3 = *(const float4*)(zp[br] + k + 12);
                a0 += z0.x * rw1[k +  0] + z0.y * rw1[k +  1] + z0.z * rw1[k +  2] + z0.w * rw1[k +  3];
                a1 += z1.x * rw1[k +  4] + z1.y * rw1[k +  5] + z1.z * rw1[k +  6] + z1.w * rw1[k +  7];
                a2 += z2.x * rw1[k +  8] + z2.y * rw1[k +  9] + z2.z * rw1[k + 10] + z2.w * rw1[k + 11];
                a3 += z3.x * rw1[k + 12] + z3.y * rw1[k + 13] + z3.z * rw1[k + 14] + z3.w * rw1[k + 15];
            }
            float hj = (a0 + a1) + (a2 + a3) + biasj;
            float cl = fminf(fmaxf(hj, -15.f), 15.f);
            float e2 = __expf(2.f * cl);
            float th = (e2 - 1.f) / (e2 + 1.f);
            wsc[br] = wave_sum(th * w2j);
        }
        float m = fmaxf(fmaxf(wsc[0], wsc[1]), fmaxf(wsc[2], wsc[3]));
        float e0 = __expf(wsc[0] - m), e1 = __expf(wsc[1] - m);
        float e2b = __expf(wsc[2] - m), e3 = __expf(wsc[3] - m);
        float inv = 1.f / (e0 + e1 + e2b + e3);
        float b0 = e0 * inv, bb = e1 * inv, b2 = e2b * inv, b3 = e3 * inv;
#pragma unroll
        for (int part = 0; part < 2; ++part) {
            int ch = lane + part * 64;
            float v = b0 * zp[0][ch] + bb * zp[1][ch] + b2 * zp[2][ch] + b3 * zp[3][ch];
            emb[(size_t)node * C + ch] = v;
        }
    }
}

extern "C" void kernel_launch(void* const* d_in, const int* in_sizes, int n_in,
                              void* d_out, int out_size, void* d_ws, size_t ws_size,
                              hipStream_t stream) {
    const float* x   = (const float*)d_in[0];
    const int* row   = (const int*)d_in[1];
    const int* col   = (const int*)d_in[2];
    const float* Wl0 = (const float*)d_in[3];
    const float* bl0 = (const float*)d_in[4];
    const float* Wr0 = (const float*)d_in[5];
    const float* Wl1 = (const float*)d_in[6];
    const float* bl1 = (const float*)d_in[7];
    const float* Wr1 = (const float*)d_in[8];
    const float* aW1 = (const float*)d_in[9];
    const float* ab1 = (const float*)d_in[10];
    const float* aW2 = (const float*)d_in[11];

    float* out = (float*)d_out;
    float* emb = out;                         // also x1 (written by gemm2 b0, finalized by attention)
    float* x3  = out + (size_t)NN * C;
    float* x4  = out + 2 * (size_t)NN * C;

    char* ws = (char*)d_ws;
    size_t off = 0;
    auto alloc = [&](size_t bytes) -> void* {
        void* p = ws + off;
        off += (bytes + 255) & ~(size_t)255;
        return p;
    };
    int* deg     = (int*)alloc((size_t)NN * 4);
    int* offsets = (int*)alloc((size_t)(NN + 1) * 4);
    int* cursor  = (int*)alloc((size_t)NN * 4);
    int* bsum    = (int*)alloc((size_t)64 * 4);
    int* colv    = (int*)alloc((size_t)NE * 4);
    float* n2    = (float*)alloc((size_t)NN * 4);
    float* n2b   = (float*)alloc((size_t)NN * 4);
    unsigned short* xbf   = (unsigned short*)alloc((size_t)NN * C * 2);
    unsigned short* aggcb = (unsigned short*)alloc((size_t)NN * C * 2);  // reused: agg1
    unsigned short* aggeb = (unsigned short*)alloc((size_t)NN * C * 2);  // reused: agg2
    unsigned short* x3b   = (unsigned short*)alloc((size_t)NN * C * 2);
    unsigned short* x4b   = (unsigned short*)alloc((size_t)NN * C * 2);
    unsigned short* Bt    = (unsigned short*)alloc((size_t)65536 * 2);
    float* x2f   = (float*)alloc((size_t)NN * C * 4);

    hipMemsetAsync(deg, 0, (size_t)NN * 4, stream);
    count_deg<<<(NE + 255) / 256, 256, 0, stream>>>(row, deg);
    deg_block_sums<<<SCAN_NB, 256, 0, stream>>>(deg, bsum);
    scan_bsums<<<1, 64, 0, stream>>>(bsum);
    scan_within<<<SCAN_NB, 256, 0, stream>>>(deg, bsum, offsets, cursor);
    bucket_edges<<<(NE + 255) / 256, 256, 0, stream>>>(row, col, cursor, colv);

    cast_x<<<(NN * C / 4 + 255) / 256, 256, 0, stream>>>(x, xbf);
    prep_w<<<256, 256, 0, stream>>>(Wl0, Wr0, Wl1, Wr1, Bt);

    norm2_kernel<<<NN / 4, 256, 0, stream>>>(x, n2);
    l1_agg<<<NN / 4, 256, 0, stream>>>(x, colv, offsets, n2, aggcb, aggeb);

    const int GB = (NN + 127) / 128;
    gemm_mfma<<<GB, 256, 0, stream>>>(aggcb, xbf, Bt, bl0, x3, x3b, 1);
    gemm_mfma<<<GB, 256, 0, stream>>>(aggeb, xbf, Bt, bl0, x4, x4b, 1);

    norm2_kernel<<<NN / 4, 256, 0, stream>>>(x3, n2b);
    l2_agg<<<NN / 4, 256, 0, stream>>>(x3, x4, colv, offsets, n2b, aggcb, aggeb);

    gemm_mfma<<<GB, 256, 0, stream>>>(aggcb, x3b, Bt + 32768, bl1, emb, nullptr, 0);
    gemm_mfma<<<GB, 256, 0, stream>>>(aggeb, x4b, Bt + 32768, bl1, x2f, nullptr, 0);

    attention<<<1024, 256, 0, stream>>>(emb, x2f, x3, x4, aW1, ab1, aW2, out);
}

// Round 5
// 699.469 us; speedup vs baseline: 2.5999x; 1.0615x over previous
//
#include <hip/hip_runtime.h>

#define NN 50000
#define NE 800000
#define C 128

typedef __attribute__((ext_vector_type(8))) short short8_t;
typedef __attribute__((ext_vector_type(4))) float f32x4;

__device__ __forceinline__ float wave_sum(float v) {
#pragma unroll
    for (int off = 32; off > 0; off >>= 1) v += __shfl_xor(v, off, 64);
    return v;
}

__device__ __forceinline__ unsigned short f2bf(float f) {
    union { float f; unsigned u; } v; v.f = f;
    unsigned r = v.u + 0x7fffu + ((v.u >> 16) & 1u);   // RNE
    return (unsigned short)(r >> 16);
}

__device__ __forceinline__ float bf2f(unsigned short u) {
    union { unsigned u; float f; } v; v.u = ((unsigned)u) << 16; return v.f;
}

// ---------------- CSR build ----------------
__global__ void count_deg(const int* __restrict__ row, int* __restrict__ deg) {
    int e = blockIdx.x * blockDim.x + threadIdx.x;
    if (e < NE) atomicAdd(&deg[row[e]], 1);
}

#define SCAN_NB ((NN + 1023) / 1024)

__global__ void deg_block_sums(const int* __restrict__ deg, int* __restrict__ bsum) {
    __shared__ int sred[256];
    int t = threadIdx.x;
    int base = blockIdx.x * 1024 + t * 4;
    int s = 0;
    if (base + 3 < NN) {
        int4 v = *(const int4*)(deg + base);
        s = v.x + v.y + v.z + v.w;
    } else {
        for (int i = 0; i < 4; ++i) if (base + i < NN) s += deg[base + i];
    }
    sred[t] = s; __syncthreads();
    for (int off = 128; off > 0; off >>= 1) {
        if (t < off) sred[t] += sred[t + off];
        __syncthreads();
    }
    if (t == 0) bsum[blockIdx.x] = sred[0];
}

__global__ void scan_bsums(int* __restrict__ bsum) {   // 1 block x 64
    int t = threadIdx.x;
    int v = (t < SCAN_NB) ? bsum[t] : 0;
#pragma unroll
    for (int off = 1; off < 64; off <<= 1) {
        int u = __shfl_up(v, off, 64);
        if (t >= off) v += u;
    }
    int ex = __shfl_up(v, 1, 64);
    if (t == 0) ex = 0;
    if (t < SCAN_NB) bsum[t] = ex;
}

__global__ void scan_within(const int* __restrict__ deg, const int* __restrict__ bsum,
                            int* __restrict__ offsets, int* __restrict__ cursor) {
    __shared__ int sdat[256];
    int t = threadIdx.x;
    int base = blockIdx.x * 1024 + t * 4;
    int d[4] = {0, 0, 0, 0};
    if (base + 3 < NN) {
        int4 v = *(const int4*)(deg + base);
        d[0] = v.x; d[1] = v.y; d[2] = v.z; d[3] = v.w;
    } else {
        for (int i = 0; i < 4; ++i) if (base + i < NN) d[i] = deg[base + i];
    }
    sdat[t] = d[0] + d[1] + d[2] + d[3];
    __syncthreads();
    for (int off = 1; off < 256; off <<= 1) {
        int v = sdat[t];
        int add = (t >= off) ? sdat[t - off] : 0;
        __syncthreads();
        sdat[t] = v + add;
        __syncthreads();
    }
    int run = bsum[blockIdx.x] + ((t == 0) ? 0 : sdat[t - 1]);
    for (int i = 0; i < 4; ++i) {
        int idx = base + i;
        if (idx < NN) { offsets[idx] = run; cursor[idx] = run; run += d[i]; }
    }
    if (blockIdx.x == 0 && t == 0) offsets[NN] = NE;
}

// bucket: store row and col VALUES at the CSR slot
__global__ void bucket_edges(const int* __restrict__ row, const int* __restrict__ col,
                             int* __restrict__ cursor, int* __restrict__ rowv,
                             int* __restrict__ colv) {
    int e = blockIdx.x * blockDim.x + threadIdx.x;
    if (e < NE) {
        int r = row[e];
        int p = atomicAdd(&cursor[r], 1);
        rowv[p] = r;
        colv[p] = col[e];
    }
}

// ---------------- per-node stats: sum of squares + plain sum ----------------
__global__ void stats_kernel(const float* __restrict__ x, float* __restrict__ n2,
                             float* __restrict__ s1) {
    int node = blockIdx.x * 4 + (threadIdx.x >> 6);
    int lane = threadIdx.x & 63;
    float2 v = *(const float2*)(x + (size_t)node * C + lane * 2);
    float sq = v.x * v.x + v.y * v.y;
    float sm = v.x + v.y;
#pragma unroll
    for (int off = 32; off > 0; off >>= 1) {
        sq += __shfl_xor(sq, off, 64);
        sm += __shfl_xor(sm, off, 64);
    }
    if (lane == 0) { n2[node] = sq; s1[node] = sm; }
}

// ---------------- cast x -> bf16 ----------------
__global__ void cast_x(const float* __restrict__ x, unsigned short* __restrict__ xbf) {
    int i = blockIdx.x * 256 + threadIdx.x;   // 4 elems each
    float4 v = ((const float4*)x)[i];
    ushort2 a; a.x = f2bf(v.x); a.y = f2bf(v.y);
    ushort2 b; b.x = f2bf(v.z); b.y = f2bf(v.w);
    ((ushort2*)xbf)[i * 2] = a;
    ((ushort2*)xbf)[i * 2 + 1] = b;
}

// ---------------- weight prep ----------------
__global__ void prep_w(const float* __restrict__ Wl0, const float* __restrict__ Wr0,
                       const float* __restrict__ Wl1, const float* __restrict__ Wr1,
                       unsigned short* __restrict__ Bt) {
    int id = blockIdx.x * 256 + threadIdx.x;   // [0, 65536)
    int layer = id >> 15;
    int c = (id >> 14) & 1;
    int n = (id >> 7) & 127;
    int kk = id & 127;
    const float* W = layer == 0 ? (c == 0 ? Wl0 : Wr0) : (c == 0 ? Wl1 : Wr1);
    Bt[id] = f2bf(W[kk * 128 + n]);
}

__global__ void prep_attw(const float* __restrict__ W1, unsigned short* __restrict__ BtA) {
    int id = blockIdx.x * 256 + threadIdx.x;   // [0, 8192)
    int col = id >> 7, k = id & 127;
    BtA[id] = f2bf(W1[k * 64 + col]);
}

// ---------------- edge similarity (layer 1): one dot per edge ----------------
// cos = dot/max(sqrt(n2r*n2c),1e-8); eud = sqrt(n2r+n2c-2dot+2e-6*(s1r-s1c)+128e-12)
__global__ __launch_bounds__(256) void edge_sim1(
    const float* __restrict__ x, const int* __restrict__ rowv, const int* __restrict__ colv,
    const float* __restrict__ n2, const float* __restrict__ s1,
    float* __restrict__ wc, float* __restrict__ we) {
    int p = blockIdx.x * 16 + (threadIdx.x >> 4);
    int lr = threadIdx.x & 15;
    int r = rowv[p], c = colv[p];
    const float4* ar = (const float4*)(x + (size_t)r * C + lr * 8);
    const float4* ac = (const float4*)(x + (size_t)c * C + lr * 8);
    float4 a0 = ar[0], a1 = ar[1], b0 = ac[0], b1 = ac[1];
    float dp = a0.x * b0.x + a0.y * b0.y + a0.z * b0.z + a0.w * b0.w
             + a1.x * b1.x + a1.y * b1.y + a1.z * b1.z + a1.w * b1.w;
#pragma unroll
    for (int off = 1; off < 16; off <<= 1) dp += __shfl_xor(dp, off, 64);
    if (lr == 0) {
        float n2r = n2[r], n2c = n2[c];
        wc[p] = dp / fmaxf(sqrtf(n2r * n2c), 1e-8f);
        float d2 = n2r + n2c - 2.f * dp + 2e-6f * (s1[r] - s1[c]) + 1.28e-10f;
        we[p] = sqrtf(fmaxf(d2, 0.f));
    }
}

// ---------------- edge similarity (layer 2): dots over x3 (cos) and x4 (eud) ----------------
__global__ __launch_bounds__(256) void edge_sim2(
    const float* __restrict__ x3, const float* __restrict__ x4,
    const int* __restrict__ rowv, const int* __restrict__ colv,
    const float* __restrict__ n2_3, const float* __restrict__ n2_4,
    const float* __restrict__ s1_4, float* __restrict__ wc, float* __restrict__ we) {
    int p = blockIdx.x * 16 + (threadIdx.x >> 4);
    int lr = threadIdx.x & 15;
    int r = rowv[p], c = colv[p];
    const float4* a3 = (const float4*)(x3 + (size_t)r * C + lr * 8);
    const float4* b3 = (const float4*)(x3 + (size_t)c * C + lr * 8);
    const float4* a4 = (const float4*)(x4 + (size_t)r * C + lr * 8);
    const float4* b4 = (const float4*)(x4 + (size_t)c * C + lr * 8);
    float4 p0 = a3[0], p1 = a3[1], q0 = b3[0], q1 = b3[1];
    float dp3 = p0.x * q0.x + p0.y * q0.y + p0.z * q0.z + p0.w * q0.w
              + p1.x * q1.x + p1.y * q1.y + p1.z * q1.z + p1.w * q1.w;
    float4 r0 = a4[0], r1 = a4[1], s0 = b4[0], s1q = b4[1];
    float dp4 = r0.x * s0.x + r0.y * s0.y + r0.z * s0.z + r0.w * s0.w
              + r1.x * s1q.x + r1.y * s1q.y + r1.z * s1q.z + r1.w * s1q.w;
#pragma unroll
    for (int off = 1; off < 16; off <<= 1) {
        dp3 += __shfl_xor(dp3, off, 64);
        dp4 += __shfl_xor(dp4, off, 64);
    }
    if (lr == 0) {
        wc[p] = dp3 / fmaxf(sqrtf(n2_3[r] * n2_3[c]), 1e-8f);
        float d2 = n2_4[r] + n2_4[c] - 2.f * dp4 + 2e-6f * (s1_4[r] - s1_4[c]) + 1.28e-10f;
        we[p] = sqrtf(fmaxf(d2, 0.f));
    }
}

// ---------------- weighted gather-aggregate (layer 1): both weights x same source ----------------
__global__ __launch_bounds__(256) void agg_l1(
    const float* __restrict__ x, const int* __restrict__ colv, const int* __restrict__ offsets,
    const float* __restrict__ wc, const float* __restrict__ we,
    unsigned short* __restrict__ aggc, unsigned short* __restrict__ agge) {
    int node = blockIdx.x * 4 + (threadIdx.x >> 6);
    int lane = threadIdx.x & 63;
    int beg = offsets[node], end = offsets[node + 1];
    float ac0 = 0.f, ac1 = 0.f, ae0 = 0.f, ae1 = 0.f;
    int p = beg;
    for (; p + 3 < end; p += 4) {
        int c0 = colv[p], c1 = colv[p + 1], c2 = colv[p + 2], c3 = colv[p + 3];
        float2 v0 = *(const float2*)(x + (size_t)c0 * C + lane * 2);
        float2 v1 = *(const float2*)(x + (size_t)c1 * C + lane * 2);
        float2 v2 = *(const float2*)(x + (size_t)c2 * C + lane * 2);
        float2 v3 = *(const float2*)(x + (size_t)c3 * C + lane * 2);
        float wc0 = wc[p], wc1 = wc[p + 1], wc2 = wc[p + 2], wc3 = wc[p + 3];
        float we0 = we[p], we1 = we[p + 1], we2 = we[p + 2], we3 = we[p + 3];
        ac0 += wc0 * v0.x + wc1 * v1.x + wc2 * v2.x + wc3 * v3.x;
        ac1 += wc0 * v0.y + wc1 * v1.y + wc2 * v2.y + wc3 * v3.y;
        ae0 += we0 * v0.x + we1 * v1.x + we2 * v2.x + we3 * v3.x;
        ae1 += we0 * v0.y + we1 * v1.y + we2 * v2.y + we3 * v3.y;
    }
    for (; p < end; ++p) {
        int c0 = colv[p];
        float2 v0 = *(const float2*)(x + (size_t)c0 * C + lane * 2);
        float wc0 = wc[p], we0 = we[p];
        ac0 += wc0 * v0.x; ac1 += wc0 * v0.y;
        ae0 += we0 * v0.x; ae1 += we0 * v0.y;
    }
    float inv = 1.f / fmaxf((float)(end - beg), 1.f);
    ushort2 uc; uc.x = f2bf(ac0 * inv); uc.y = f2bf(ac1 * inv);
    ushort2 ue; ue.x = f2bf(ae0 * inv); ue.y = f2bf(ae1 * inv);
    *(ushort2*)(aggc + (size_t)node * C + lane * 2) = uc;
    *(ushort2*)(agge + (size_t)node * C + lane * 2) = ue;
}

// ---------------- weighted gather-aggregate (layer 2): wc x3, we x4 ----------------
__global__ __launch_bounds__(256) void agg_l2(
    const float* __restrict__ x3, const float* __restrict__ x4,
    const int* __restrict__ colv, const int* __restrict__ offsets,
    const float* __restrict__ wc, const float* __restrict__ we,
    unsigned short* __restrict__ agg1, unsigned short* __restrict__ agg2) {
    int node = blockIdx.x * 4 + (threadIdx.x >> 6);
    int lane = threadIdx.x & 63;
    int beg = offsets[node], end = offsets[node + 1];
    float a10 = 0.f, a11 = 0.f, a20 = 0.f, a21 = 0.f;
    int p = beg;
    for (; p + 1 < end; p += 2) {
        int c0 = colv[p], c1 = colv[p + 1];
        float2 u0 = *(const float2*)(x3 + (size_t)c0 * C + lane * 2);
        float2 u1 = *(const float2*)(x3 + (size_t)c1 * C + lane * 2);
        float2 v0 = *(const float2*)(x4 + (size_t)c0 * C + lane * 2);
        float2 v1 = *(const float2*)(x4 + (size_t)c1 * C + lane * 2);
        float wc0 = wc[p], wc1 = wc[p + 1], we0 = we[p], we1 = we[p + 1];
        a10 += wc0 * u0.x + wc1 * u1.x;
        a11 += wc0 * u0.y + wc1 * u1.y;
        a20 += we0 * v0.x + we1 * v1.x;
        a21 += we0 * v0.y + we1 * v1.y;
    }
    if (p < end) {
        int c0 = colv[p];
        float2 u0 = *(const float2*)(x3 + (size_t)c0 * C + lane * 2);
        float2 v0 = *(const float2*)(x4 + (size_t)c0 * C + lane * 2);
        float wc0 = wc[p], we0 = we[p];
        a10 += wc0 * u0.x; a11 += wc0 * u0.y;
        a20 += we0 * v0.x; a21 += we0 * v0.y;
    }
    float inv = 1.f / fmaxf((float)(end - beg), 1.f);
    ushort2 u1o; u1o.x = f2bf(a10 * inv); u1o.y = f2bf(a11 * inv);
    ushort2 u2o; u2o.x = f2bf(a20 * inv); u2o.y = f2bf(a21 * inv);
    *(ushort2*)(agg1 + (size_t)node * C + lane * 2) = u1o;
    *(ushort2*)(agg2 + (size_t)node * C + lane * 2) = u2o;
}

// ---------------- MFMA GEMM: C[n,128] = [A0|A1](n, 256) @ B(256,128) + bias ----------------
__global__ __launch_bounds__(256) void gemm_mfma(
    const unsigned short* __restrict__ A0, const unsigned short* __restrict__ A1,
    const unsigned short* __restrict__ Bt, const float* __restrict__ bias,
    float* __restrict__ Cout, unsigned short* __restrict__ Cbf, int relu) {
    __shared__ __align__(16) unsigned short sA[128 * 136];
    __shared__ __align__(16) unsigned short sB[128 * 136];
    const int tx = threadIdx.x;
    const int l = tx & 63;
    const int wv = tx >> 6;
    const int wm = wv >> 1, wn = wv & 1;
    const int lr = l & 15;
    const int lq = l >> 4;
    const int n0 = blockIdx.x * 128;

    f32x4 acc[4][4] = {};
    for (int c = 0; c < 2; ++c) {
        const unsigned short* Ac = (c == 0) ? A0 : A1;
#pragma unroll
        for (int it = 0; it < 8; ++it) {
            int idx = it * 256 + tx;
            int r = idx >> 4, s = idx & 15;
            int n = n0 + r; n = n < NN ? n : NN - 1;
            *(short8_t*)(sA + r * 136 + s * 8) = *(const short8_t*)(Ac + (size_t)n * 128 + s * 8);
            *(short8_t*)(sB + r * 136 + s * 8) = *(const short8_t*)(Bt + c * 16384 + idx * 8);
        }
        __syncthreads();
#pragma unroll
        for (int ks = 0; ks < 4; ++ks) {
            short8_t af[4], bfr[4];
#pragma unroll
            for (int t = 0; t < 4; ++t) {
                af[t]  = *(const short8_t*)(sA + (wm * 64 + t * 16 + lr) * 136 + ks * 32 + lq * 8);
                bfr[t] = *(const short8_t*)(sB + (wn * 64 + t * 16 + lr) * 136 + ks * 32 + lq * 8);
            }
#pragma unroll
            for (int mt = 0; mt < 4; ++mt)
#pragma unroll
                for (int nt = 0; nt < 4; ++nt)
                    acc[mt][nt] = __builtin_amdgcn_mfma_f32_16x16x32_bf16(af[mt], bfr[nt], acc[mt][nt], 0, 0, 0);
        }
        __syncthreads();
    }
#pragma unroll
    for (int mt = 0; mt < 4; ++mt) {
        int rbase = wm * 64 + mt * 16 + lq * 4;
#pragma unroll
        for (int nt = 0; nt < 4; ++nt) {
            int col = wn * 64 + nt * 16 + lr;
            float bv = bias[col];
#pragma unroll
            for (int rg = 0; rg < 4; ++rg) {
                int n = n0 + rbase + rg;
                if (n < NN) {
                    float y = acc[mt][nt][rg] + bv;
                    if (relu) y = fmaxf(y, 0.f);
                    if (Cout) Cout[(size_t)n * 128 + col] = y;
                    if (Cbf) Cbf[(size_t)n * 128 + col] = f2bf(y);
                }
            }
        }
    }
}

// ---------------- attention scores via MFMA: w[node][br] = tanh(z@W1+b1)@W2 ----------------
// block: 32 nodes x 4 branches = 128 rows; N=64, K=128
__global__ __launch_bounds__(256) void att_score(
    const unsigned short* __restrict__ x1b, const unsigned short* __restrict__ x2b,
    const unsigned short* __restrict__ x3b, const unsigned short* __restrict__ x4b,
    const unsigned short* __restrict__ BtA, const float* __restrict__ b1,
    const float* __restrict__ W2, float* __restrict__ wout) {
    __shared__ __align__(16) unsigned short sA[128 * 136];
    __shared__ __align__(16) unsigned short sB[64 * 136];
    const int tx = threadIdx.x;
    const int n0 = blockIdx.x * 32;
    const unsigned short* zb[4] = {x1b, x2b, x3b, x4b};
#pragma unroll
    for (int it = 0; it < 8; ++it) {
        int idx = it * 256 + tx;
        int r = idx >> 4, s = idx & 15;
        int node = n0 + (r >> 2); node = node < NN ? node : NN - 1;
        *(short8_t*)(sA + r * 136 + s * 8) = *(const short8_t*)(zb[r & 3] + (size_t)node * 128 + s * 8);
    }
#pragma unroll
    for (int it = 0; it < 4; ++it) {
        int idx = it * 256 + tx;
        int r = idx >> 4, s = idx & 15;
        *(short8_t*)(sB + r * 136 + s * 8) = *(const short8_t*)(BtA + idx * 8);
    }
    __syncthreads();
    const int w = tx >> 6, lane = tx & 63, lr = lane & 15, lq = lane >> 4;
    f32x4 acc[2][4] = {};
#pragma unroll
    for (int ks = 0; ks < 4; ++ks) {
        short8_t af[2], bfr[4];
#pragma unroll
        for (int mt = 0; mt < 2; ++mt)
            af[mt] = *(const short8_t*)(sA + (w * 32 + mt * 16 + lr) * 136 + ks * 32 + lq * 8);
#pragma unroll
        for (int nt = 0; nt < 4; ++nt)
            bfr[nt] = *(const short8_t*)(sB + (nt * 16 + lr) * 136 + ks * 32 + lq * 8);
#pragma unroll
        for (int mt = 0; mt < 2; ++mt)
#pragma unroll
            for (int nt = 0; nt < 4; ++nt)
                acc[mt][nt] = __builtin_amdgcn_mfma_f32_16x16x32_bf16(af[mt], bfr[nt], acc[mt][nt], 0, 0, 0);
    }
#pragma unroll
    for (int mt = 0; mt < 2; ++mt) {
        float part[4] = {0.f, 0.f, 0.f, 0.f};
#pragma unroll
        for (int nt = 0; nt < 4; ++nt) {
            int col = nt * 16 + lr;
            float bb = b1[col], w2 = W2[col];
#pragma unroll
            for (int rg = 0; rg < 4; ++rg) {
                float h = acc[mt][nt][rg] + bb;
                float cl = fminf(fmaxf(h, -15.f), 15.f);
                float e2 = __expf(2.f * cl);
                part[rg] += (e2 - 1.f) / (e2 + 1.f) * w2;
            }
        }
#pragma unroll
        for (int rg = 0; rg < 4; ++rg)
#pragma unroll
            for (int off = 1; off < 16; off <<= 1)
                part[rg] += __shfl_xor(part[rg], off, 64);
        if (lr == 0) {
#pragma unroll
            for (int rg = 0; rg < 4; ++rg) {
                int r = w * 32 + mt * 16 + lq * 4 + rg;
                int node = n0 + (r >> 2);
                if (node < NN) wout[(size_t)node * 4 + (r & 3)] = part[rg];
            }
        }
    }
}

// ---------------- softmax + weighted combine ----------------
__global__ __launch_bounds__(256) void att_combine(
    const float* __restrict__ x1, const unsigned short* __restrict__ x2b,
    const float* __restrict__ x3, const float* __restrict__ x4,
    const float* __restrict__ wsc, float* __restrict__ emb) {
    int node = blockIdx.x * 4 + (threadIdx.x >> 6);
    int lane = threadIdx.x & 63;
    float4 w = *(const float4*)(wsc + (size_t)node * 4);
    float m = fmaxf(fmaxf(w.x, w.y), fmaxf(w.z, w.w));
    float e0 = __expf(w.x - m), e1 = __expf(w.y - m), e2 = __expf(w.z - m), e3 = __expf(w.w - m);
    float inv = 1.f / (e0 + e1 + e2 + e3);
    float b0 = e0 * inv, b1 = e1 * inv, b2 = e2 * inv, b3 = e3 * inv;
    size_t base = (size_t)node * C + lane * 2;
    float2 z1 = *(const float2*)(x1 + base);
    ushort2 u2 = *(const ushort2*)(x2b + base);
    float2 z3 = *(const float2*)(x3 + base);
    float2 z4 = *(const float2*)(x4 + base);
    float2 o;
    o.x = b0 * z1.x + b1 * bf2f(u2.x) + b2 * z3.x + b3 * z4.x;
    o.y = b0 * z1.y + b1 * bf2f(u2.y) + b2 * z3.y + b3 * z4.y;
    *(float2*)(emb + base) = o;
}

extern "C" void kernel_launch(void* const* d_in, const int* in_sizes, int n_in,
                              void* d_out, int out_size, void* d_ws, size_t ws_size,
                              hipStream_t stream) {
    const float* x   = (const float*)d_in[0];
    const int* row   = (const int*)d_in[1];
    const int* col   = (const int*)d_in[2];
    const float* Wl0 = (const float*)d_in[3];
    const float* bl0 = (const float*)d_in[4];
    const float* Wr0 = (const float*)d_in[5];
    const float* Wl1 = (const float*)d_in[6];
    const float* bl1 = (const float*)d_in[7];
    const float* Wr1 = (const float*)d_in[8];
    const float* aW1 = (const float*)d_in[9];
    const float* ab1 = (const float*)d_in[10];
    const float* aW2 = (const float*)d_in[11];

    float* out = (float*)d_out;
    float* emb = out;                         // x1 fp32 lives here until att_combine overwrites
    float* x3  = out + (size_t)NN * C;
    float* x4  = out + 2 * (size_t)NN * C;

    char* ws = (char*)d_ws;
    size_t off = 0;
    auto alloc = [&](size_t bytes) -> void* {
        void* p = ws + off;
        off += (bytes + 255) & ~(size_t)255;
        return p;
    };
    int* deg     = (int*)alloc((size_t)NN * 4);
    int* offsets = (int*)alloc((size_t)(NN + 1) * 4);
    int* cursor  = (int*)alloc((size_t)NN * 4);
    int* bsum    = (int*)alloc((size_t)64 * 4);
    int* rowv    = (int*)alloc((size_t)NE * 4);
    int* colv    = (int*)alloc((size_t)NE * 4);
    float* n2    = (float*)alloc((size_t)NN * 4);
    float* s1    = (float*)alloc((size_t)NN * 4);
    float* n2_3  = (float*)alloc((size_t)NN * 4);
    float* s1_3  = (float*)alloc((size_t)NN * 4);
    float* n2_4  = (float*)alloc((size_t)NN * 4);
    float* s1_4  = (float*)alloc((size_t)NN * 4);
    float* wc    = (float*)alloc((size_t)NE * 4);   // reused for layer 2
    float* we    = (float*)alloc((size_t)NE * 4);   // reused for layer 2
    unsigned short* xbf   = (unsigned short*)alloc((size_t)NN * C * 2);  // reused as x1b
    unsigned short* aggcb = (unsigned short*)alloc((size_t)NN * C * 2);  // reused: agg1
    unsigned short* aggeb = (unsigned short*)alloc((size_t)NN * C * 2);  // reused: agg2
    unsigned short* x3b   = (unsigned short*)alloc((size_t)NN * C * 2);
    unsigned short* x4b   = (unsigned short*)alloc((size_t)NN * C * 2);
    unsigned short* x2b   = (unsigned short*)alloc((size_t)NN * C * 2);
    unsigned short* Bt    = (unsigned short*)alloc((size_t)65536 * 2);
    unsigned short* BtA   = (unsigned short*)alloc((size_t)8192 * 2);
    float* wout  = (float*)alloc((size_t)NN * 4 * 4);

    hipMemsetAsync(deg, 0, (size_t)NN * 4, stream);
    count_deg<<<(NE + 255) / 256, 256, 0, stream>>>(row, deg);
    deg_block_sums<<<SCAN_NB, 256, 0, stream>>>(deg, bsum);
    scan_bsums<<<1, 64, 0, stream>>>(bsum);
    scan_within<<<SCAN_NB, 256, 0, stream>>>(deg, bsum, offsets, cursor);
    bucket_edges<<<(NE + 255) / 256, 256, 0, stream>>>(row, col, cursor, rowv, colv);

    cast_x<<<(NN * C / 4 + 255) / 256, 256, 0, stream>>>(x, xbf);
    prep_w<<<256, 256, 0, stream>>>(Wl0, Wr0, Wl1, Wr1, Bt);
    prep_attw<<<32, 256, 0, stream>>>(aW1, BtA);

    stats_kernel<<<NN / 4, 256, 0, stream>>>(x, n2, s1);
    edge_sim1<<<NE / 16, 256, 0, stream>>>(x, rowv, colv, n2, s1, wc, we);
    agg_l1<<<NN / 4, 256, 0, stream>>>(x, colv, offsets, wc, we, aggcb, aggeb);

    const int GB = (NN + 127) / 128;
    gemm_mfma<<<GB, 256, 0, stream>>>(aggcb, xbf, Bt, bl0, x3, x3b, 1);
    gemm_mfma<<<GB, 256, 0, stream>>>(aggeb, xbf, Bt, bl0, x4, x4b, 1);

    stats_kernel<<<NN / 4, 256, 0, stream>>>(x3, n2_3, s1_3);
    stats_kernel<<<NN / 4, 256, 0, stream>>>(x4, n2_4, s1_4);
    edge_sim2<<<NE / 16, 256, 0, stream>>>(x3, x4, rowv, colv, n2_3, n2_4, s1_4, wc, we);
    agg_l2<<<NN / 4, 256, 0, stream>>>(x3, x4, colv, offsets, wc, we, aggcb, aggeb);

    gemm_mfma<<<GB, 256, 0, stream>>>(aggcb, x3b, Bt + 32768, bl1, emb, xbf /*x1b*/, 0);
    gemm_mfma<<<GB, 256, 0, stream>>>(aggeb, x4b, Bt + 32768, bl1, nullptr, x2b, 0);

    att_score<<<(NN + 31) / 32, 256, 0, stream>>>(xbf, x2b, x3b, x4b, BtA, ab1, aW2, wout);
    att_combine<<<NN / 4, 256, 0, stream>>>(emb, x2b, x3, x4, wout, emb);
}

// Round 6
// 555.767 us; speedup vs baseline: 3.2722x; 1.2586x over previous
//
#include <hip/hip_runtime.h>

#define NN 50000
#define NE 800000
#define C 128

typedef __attribute__((ext_vector_type(8))) short short8_t;
typedef __attribute__((ext_vector_type(4))) float f32x4;

__device__ __forceinline__ unsigned short f2bf(float f) {
    union { float f; unsigned u; } v; v.f = f;
    unsigned r = v.u + 0x7fffu + ((v.u >> 16) & 1u);   // RNE
    return (unsigned short)(r >> 16);
}

__device__ __forceinline__ float bf2f(unsigned short u) {
    union { unsigned u; float f; } v; v.u = ((unsigned)u) << 16; return v.f;
}

__device__ __forceinline__ float bf2f_s(short s) { return bf2f((unsigned short)s); }

// ---------------- CSR build ----------------
__global__ void count_deg(const int* __restrict__ row, int* __restrict__ deg) {
    int e = blockIdx.x * blockDim.x + threadIdx.x;
    if (e < NE) atomicAdd(&deg[row[e]], 1);
}

#define SCAN_NB ((NN + 1023) / 1024)

__global__ void deg_block_sums(const int* __restrict__ deg, int* __restrict__ bsum) {
    __shared__ int sred[256];
    int t = threadIdx.x;
    int base = blockIdx.x * 1024 + t * 4;
    int s = 0;
    if (base + 3 < NN) {
        int4 v = *(const int4*)(deg + base);
        s = v.x + v.y + v.z + v.w;
    } else {
        for (int i = 0; i < 4; ++i) if (base + i < NN) s += deg[base + i];
    }
    sred[t] = s; __syncthreads();
    for (int off = 128; off > 0; off >>= 1) {
        if (t < off) sred[t] += sred[t + off];
        __syncthreads();
    }
    if (t == 0) bsum[blockIdx.x] = sred[0];
}

__global__ void scan_bsums(int* __restrict__ bsum) {   // 1 block x 64
    int t = threadIdx.x;
    int v = (t < SCAN_NB) ? bsum[t] : 0;
#pragma unroll
    for (int off = 1; off < 64; off <<= 1) {
        int u = __shfl_up(v, off, 64);
        if (t >= off) v += u;
    }
    int ex = __shfl_up(v, 1, 64);
    if (t == 0) ex = 0;
    if (t < SCAN_NB) bsum[t] = ex;
}

__global__ void scan_within(const int* __restrict__ deg, const int* __restrict__ bsum,
                            int* __restrict__ offsets, int* __restrict__ cursor) {
    __shared__ int sdat[256];
    int t = threadIdx.x;
    int base = blockIdx.x * 1024 + t * 4;
    int d[4] = {0, 0, 0, 0};
    if (base + 3 < NN) {
        int4 v = *(const int4*)(deg + base);
        d[0] = v.x; d[1] = v.y; d[2] = v.z; d[3] = v.w;
    } else {
        for (int i = 0; i < 4; ++i) if (base + i < NN) d[i] = deg[base + i];
    }
    sdat[t] = d[0] + d[1] + d[2] + d[3];
    __syncthreads();
    for (int off = 1; off < 256; off <<= 1) {
        int v = sdat[t];
        int add = (t >= off) ? sdat[t - off] : 0;
        __syncthreads();
        sdat[t] = v + add;
        __syncthreads();
    }
    int run = bsum[blockIdx.x] + ((t == 0) ? 0 : sdat[t - 1]);
    for (int i = 0; i < 4; ++i) {
        int idx = base + i;
        if (idx < NN) { offsets[idx] = run; cursor[idx] = run; run += d[i]; }
    }
    if (blockIdx.x == 0 && t == 0) offsets[NN] = NE;
}

__global__ void bucket_edges(const int* __restrict__ row, const int* __restrict__ col,
                             int* __restrict__ cursor, int* __restrict__ rowv,
                             int* __restrict__ colv) {
    int e = blockIdx.x * blockDim.x + threadIdx.x;
    if (e < NE) {
        int r = row[e];
        int p = atomicAdd(&cursor[r], 1);
        rowv[p] = r;
        colv[p] = col[e];
    }
}

// ---------------- per-node stats: sum of squares + plain sum ----------------
__global__ void stats_kernel(const float* __restrict__ x, float* __restrict__ n2,
                             float* __restrict__ s1) {
    int node = blockIdx.x * 4 + (threadIdx.x >> 6);
    int lane = threadIdx.x & 63;
    float2 v = *(const float2*)(x + (size_t)node * C + lane * 2);
    float sq = v.x * v.x + v.y * v.y;
    float sm = v.x + v.y;
#pragma unroll
    for (int off = 32; off > 0; off >>= 1) {
        sq += __shfl_xor(sq, off, 64);
        sm += __shfl_xor(sm, off, 64);
    }
    if (lane == 0) { n2[node] = sq; s1[node] = sm; }
}

// ---------------- cast x -> bf16 ----------------
__global__ void cast_x(const float* __restrict__ x, unsigned short* __restrict__ xbf) {
    int i = blockIdx.x * 256 + threadIdx.x;   // 4 elems each
    float4 v = ((const float4*)x)[i];
    ushort2 a; a.x = f2bf(v.x); a.y = f2bf(v.y);
    ushort2 b; b.x = f2bf(v.z); b.y = f2bf(v.w);
    ((ushort2*)xbf)[i * 2] = a;
    ((ushort2*)xbf)[i * 2 + 1] = b;
}

// ---------------- weight prep ----------------
__global__ void prep_w(const float* __restrict__ Wl0, const float* __restrict__ Wr0,
                       const float* __restrict__ Wl1, const float* __restrict__ Wr1,
                       unsigned short* __restrict__ Bt) {
    int id = blockIdx.x * 256 + threadIdx.x;   // [0, 65536)
    int layer = id >> 15;
    int c = (id >> 14) & 1;
    int n = (id >> 7) & 127;
    int kk = id & 127;
    const float* W = layer == 0 ? (c == 0 ? Wl0 : Wr0) : (c == 0 ? Wl1 : Wr1);
    Bt[id] = f2bf(W[kk * 128 + n]);
}

__global__ void prep_attw(const float* __restrict__ W1, unsigned short* __restrict__ BtA) {
    int id = blockIdx.x * 256 + threadIdx.x;   // [0, 8192)
    int col = id >> 7, k = id & 127;
    BtA[id] = f2bf(W1[k * 64 + col]);
}

// ---------------- edge similarity (layer 1): bf16 rows, one dot per edge ----------------
__global__ __launch_bounds__(256) void edge_sim1(
    const unsigned short* __restrict__ xb, const int* __restrict__ rowv,
    const int* __restrict__ colv, const float* __restrict__ n2, const float* __restrict__ s1,
    float* __restrict__ wc, float* __restrict__ we) {
    int p = blockIdx.x * 16 + (threadIdx.x >> 4);
    int lr = threadIdx.x & 15;
    int r = rowv[p], c = colv[p];
    short8_t ar = *(const short8_t*)(xb + (size_t)r * C + lr * 8);
    short8_t ac = *(const short8_t*)(xb + (size_t)c * C + lr * 8);
    float dp = 0.f;
#pragma unroll
    for (int i = 0; i < 8; ++i) dp += bf2f_s(ar[i]) * bf2f_s(ac[i]);
#pragma unroll
    for (int off = 1; off < 16; off <<= 1) dp += __shfl_xor(dp, off, 64);
    if (lr == 0) {
        float n2r = n2[r], n2c = n2[c];
        wc[p] = dp / fmaxf(sqrtf(n2r * n2c), 1e-8f);
        float d2 = n2r + n2c - 2.f * dp + 2e-6f * (s1[r] - s1[c]) + 1.28e-10f;
        we[p] = sqrtf(fmaxf(d2, 0.f));
    }
}

// ---------------- edge similarity (layer 2): bf16 dots over x3b (cos) and x4b (eud) ----------------
__global__ __launch_bounds__(256) void edge_sim2(
    const unsigned short* __restrict__ x3b, const unsigned short* __restrict__ x4b,
    const int* __restrict__ rowv, const int* __restrict__ colv,
    const float* __restrict__ n2_3, const float* __restrict__ n2_4,
    const float* __restrict__ s1_4, float* __restrict__ wc, float* __restrict__ we) {
    int p = blockIdx.x * 16 + (threadIdx.x >> 4);
    int lr = threadIdx.x & 15;
    int r = rowv[p], c = colv[p];
    short8_t a3 = *(const short8_t*)(x3b + (size_t)r * C + lr * 8);
    short8_t b3 = *(const short8_t*)(x3b + (size_t)c * C + lr * 8);
    short8_t a4 = *(const short8_t*)(x4b + (size_t)r * C + lr * 8);
    short8_t b4 = *(const short8_t*)(x4b + (size_t)c * C + lr * 8);
    float dp3 = 0.f, dp4 = 0.f;
#pragma unroll
    for (int i = 0; i < 8; ++i) {
        dp3 += bf2f_s(a3[i]) * bf2f_s(b3[i]);
        dp4 += bf2f_s(a4[i]) * bf2f_s(b4[i]);
    }
#pragma unroll
    for (int off = 1; off < 16; off <<= 1) {
        dp3 += __shfl_xor(dp3, off, 64);
        dp4 += __shfl_xor(dp4, off, 64);
    }
    if (lr == 0) {
        wc[p] = dp3 / fmaxf(sqrtf(n2_3[r] * n2_3[c]), 1e-8f);
        float d2 = n2_4[r] + n2_4[c] - 2.f * dp4 + 2e-6f * (s1_4[r] - s1_4[c]) + 1.28e-10f;
        we[p] = sqrtf(fmaxf(d2, 0.f));
    }
}

// ---------------- weighted gather-aggregate (layer 1): bf16 gather, both weights ----------------
__global__ __launch_bounds__(256) void agg_l1(
    const unsigned short* __restrict__ xb, const int* __restrict__ colv,
    const int* __restrict__ offsets, const float* __restrict__ wc, const float* __restrict__ we,
    unsigned short* __restrict__ aggc, unsigned short* __restrict__ agge) {
    int node = blockIdx.x * 4 + (threadIdx.x >> 6);
    int lane = threadIdx.x & 63;
    int beg = offsets[node], end = offsets[node + 1];
    float ac0 = 0.f, ac1 = 0.f, ae0 = 0.f, ae1 = 0.f;
    int p = beg;
    for (; p + 3 < end; p += 4) {
        int c0 = colv[p], c1 = colv[p + 1], c2 = colv[p + 2], c3 = colv[p + 3];
        ushort2 u0 = *(const ushort2*)(xb + (size_t)c0 * C + lane * 2);
        ushort2 u1 = *(const ushort2*)(xb + (size_t)c1 * C + lane * 2);
        ushort2 u2 = *(const ushort2*)(xb + (size_t)c2 * C + lane * 2);
        ushort2 u3 = *(const ushort2*)(xb + (size_t)c3 * C + lane * 2);
        float wc0 = wc[p], wc1 = wc[p + 1], wc2 = wc[p + 2], wc3 = wc[p + 3];
        float we0 = we[p], we1 = we[p + 1], we2 = we[p + 2], we3 = we[p + 3];
        float v0x = bf2f(u0.x), v0y = bf2f(u0.y);
        float v1x = bf2f(u1.x), v1y = bf2f(u1.y);
        float v2x = bf2f(u2.x), v2y = bf2f(u2.y);
        float v3x = bf2f(u3.x), v3y = bf2f(u3.y);
        ac0 += wc0 * v0x + wc1 * v1x + wc2 * v2x + wc3 * v3x;
        ac1 += wc0 * v0y + wc1 * v1y + wc2 * v2y + wc3 * v3y;
        ae0 += we0 * v0x + we1 * v1x + we2 * v2x + we3 * v3x;
        ae1 += we0 * v0y + we1 * v1y + we2 * v2y + we3 * v3y;
    }
    for (; p < end; ++p) {
        int c0 = colv[p];
        ushort2 u0 = *(const ushort2*)(xb + (size_t)c0 * C + lane * 2);
        float wc0 = wc[p], we0 = we[p];
        float v0x = bf2f(u0.x), v0y = bf2f(u0.y);
        ac0 += wc0 * v0x; ac1 += wc0 * v0y;
        ae0 += we0 * v0x; ae1 += we0 * v0y;
    }
    float inv = 1.f / fmaxf((float)(end - beg), 1.f);
    ushort2 uc; uc.x = f2bf(ac0 * inv); uc.y = f2bf(ac1 * inv);
    ushort2 ue; ue.x = f2bf(ae0 * inv); ue.y = f2bf(ae1 * inv);
    *(ushort2*)(aggc + (size_t)node * C + lane * 2) = uc;
    *(ushort2*)(agge + (size_t)node * C + lane * 2) = ue;
}

// ---------------- weighted gather-aggregate (layer 2): bf16 gathers, wc x3b, we x4b ----------------
__global__ __launch_bounds__(256) void agg_l2(
    const unsigned short* __restrict__ x3b, const unsigned short* __restrict__ x4b,
    const int* __restrict__ colv, const int* __restrict__ offsets,
    const float* __restrict__ wc, const float* __restrict__ we,
    unsigned short* __restrict__ agg1, unsigned short* __restrict__ agg2) {
    int node = blockIdx.x * 4 + (threadIdx.x >> 6);
    int lane = threadIdx.x & 63;
    int beg = offsets[node], end = offsets[node + 1];
    float a10 = 0.f, a11 = 0.f, a20 = 0.f, a21 = 0.f;
    int p = beg;
    for (; p + 1 < end; p += 2) {
        int c0 = colv[p], c1 = colv[p + 1];
        ushort2 u0 = *(const ushort2*)(x3b + (size_t)c0 * C + lane * 2);
        ushort2 u1 = *(const ushort2*)(x3b + (size_t)c1 * C + lane * 2);
        ushort2 v0 = *(const ushort2*)(x4b + (size_t)c0 * C + lane * 2);
        ushort2 v1 = *(const ushort2*)(x4b + (size_t)c1 * C + lane * 2);
        float wc0 = wc[p], wc1 = wc[p + 1], we0 = we[p], we1 = we[p + 1];
        a10 += wc0 * bf2f(u0.x) + wc1 * bf2f(u1.x);
        a11 += wc0 * bf2f(u0.y) + wc1 * bf2f(u1.y);
        a20 += we0 * bf2f(v0.x) + we1 * bf2f(v1.x);
        a21 += we0 * bf2f(v0.y) + we1 * bf2f(v1.y);
    }
    if (p < end) {
        int c0 = colv[p];
        ushort2 u0 = *(const ushort2*)(x3b + (size_t)c0 * C + lane * 2);
        ushort2 v0 = *(const ushort2*)(x4b + (size_t)c0 * C + lane * 2);
        float wc0 = wc[p], we0 = we[p];
        a10 += wc0 * bf2f(u0.x); a11 += wc0 * bf2f(u0.y);
        a20 += we0 * bf2f(v0.x); a21 += we0 * bf2f(v0.y);
    }
    float inv = 1.f / fmaxf((float)(end - beg), 1.f);
    ushort2 u1o; u1o.x = f2bf(a10 * inv); u1o.y = f2bf(a11 * inv);
    ushort2 u2o; u2o.x = f2bf(a20 * inv); u2o.y = f2bf(a21 * inv);
    *(ushort2*)(agg1 + (size_t)node * C + lane * 2) = u1o;
    *(ushort2*)(agg2 + (size_t)node * C + lane * 2) = u2o;
}

// ---------------- MFMA GEMM: C[n,128] = [A0|A1](n, 256) @ B(256,128) + bias ----------------
__global__ __launch_bounds__(256) void gemm_mfma(
    const unsigned short* __restrict__ A0, const unsigned short* __restrict__ A1,
    const unsigned short* __restrict__ Bt, const float* __restrict__ bias,
    float* __restrict__ Cout, unsigned short* __restrict__ Cbf, int relu) {
    __shared__ __align__(16) unsigned short sA[128 * 136];
    __shared__ __align__(16) unsigned short sB[128 * 136];
    const int tx = threadIdx.x;
    const int l = tx & 63;
    const int wv = tx >> 6;
    const int wm = wv >> 1, wn = wv & 1;
    const int lr = l & 15;
    const int lq = l >> 4;
    const int n0 = blockIdx.x * 128;

    f32x4 acc[4][4] = {};
    for (int c = 0; c < 2; ++c) {
        const unsigned short* Ac = (c == 0) ? A0 : A1;
#pragma unroll
        for (int it = 0; it < 8; ++it) {
            int idx = it * 256 + tx;
            int r = idx >> 4, s = idx & 15;
            int n = n0 + r; n = n < NN ? n : NN - 1;
            *(short8_t*)(sA + r * 136 + s * 8) = *(const short8_t*)(Ac + (size_t)n * 128 + s * 8);
            *(short8_t*)(sB + r * 136 + s * 8) = *(const short8_t*)(Bt + c * 16384 + idx * 8);
        }
        __syncthreads();
#pragma unroll
        for (int ks = 0; ks < 4; ++ks) {
            short8_t af[4], bfr[4];
#pragma unroll
            for (int t = 0; t < 4; ++t) {
                af[t]  = *(const short8_t*)(sA + (wm * 64 + t * 16 + lr) * 136 + ks * 32 + lq * 8);
                bfr[t] = *(const short8_t*)(sB + (wn * 64 + t * 16 + lr) * 136 + ks * 32 + lq * 8);
            }
#pragma unroll
            for (int mt = 0; mt < 4; ++mt)
#pragma unroll
                for (int nt = 0; nt < 4; ++nt)
                    acc[mt][nt] = __builtin_amdgcn_mfma_f32_16x16x32_bf16(af[mt], bfr[nt], acc[mt][nt], 0, 0, 0);
        }
        __syncthreads();
    }
#pragma unroll
    for (int mt = 0; mt < 4; ++mt) {
        int rbase = wm * 64 + mt * 16 + lq * 4;
#pragma unroll
        for (int nt = 0; nt < 4; ++nt) {
            int col = wn * 64 + nt * 16 + lr;
            float bv = bias[col];
#pragma unroll
            for (int rg = 0; rg < 4; ++rg) {
                int n = n0 + rbase + rg;
                if (n < NN) {
                    float y = acc[mt][nt][rg] + bv;
                    if (relu) y = fmaxf(y, 0.f);
                    if (Cout) Cout[(size_t)n * 128 + col] = y;
                    if (Cbf) Cbf[(size_t)n * 128 + col] = f2bf(y);
                }
            }
        }
    }
}

// ---------------- attention scores via MFMA ----------------
__global__ __launch_bounds__(256) void att_score(
    const unsigned short* __restrict__ x1b, const unsigned short* __restrict__ x2b,
    const unsigned short* __restrict__ x3b, const unsigned short* __restrict__ x4b,
    const unsigned short* __restrict__ BtA, const float* __restrict__ b1,
    const float* __restrict__ W2, float* __restrict__ wout) {
    __shared__ __align__(16) unsigned short sA[128 * 136];
    __shared__ __align__(16) unsigned short sB[64 * 136];
    const int tx = threadIdx.x;
    const int n0 = blockIdx.x * 32;
    const unsigned short* zb[4] = {x1b, x2b, x3b, x4b};
#pragma unroll
    for (int it = 0; it < 8; ++it) {
        int idx = it * 256 + tx;
        int r = idx >> 4, s = idx & 15;
        int node = n0 + (r >> 2); node = node < NN ? node : NN - 1;
        *(short8_t*)(sA + r * 136 + s * 8) = *(const short8_t*)(zb[r & 3] + (size_t)node * 128 + s * 8);
    }
#pragma unroll
    for (int it = 0; it < 4; ++it) {
        int idx = it * 256 + tx;
        int r = idx >> 4, s = idx & 15;
        *(short8_t*)(sB + r * 136 + s * 8) = *(const short8_t*)(BtA + idx * 8);
    }
    __syncthreads();
    const int w = tx >> 6, lane = tx & 63, lr = lane & 15, lq = lane >> 4;
    f32x4 acc[2][4] = {};
#pragma unroll
    for (int ks = 0; ks < 4; ++ks) {
        short8_t af[2], bfr[4];
#pragma unroll
        for (int mt = 0; mt < 2; ++mt)
            af[mt] = *(const short8_t*)(sA + (w * 32 + mt * 16 + lr) * 136 + ks * 32 + lq * 8);
#pragma unroll
        for (int nt = 0; nt < 4; ++nt)
            bfr[nt] = *(const short8_t*)(sB + (nt * 16 + lr) * 136 + ks * 32 + lq * 8);
#pragma unroll
        for (int mt = 0; mt < 2; ++mt)
#pragma unroll
            for (int nt = 0; nt < 4; ++nt)
                acc[mt][nt] = __builtin_amdgcn_mfma_f32_16x16x32_bf16(af[mt], bfr[nt], acc[mt][nt], 0, 0, 0);
    }
#pragma unroll
    for (int mt = 0; mt < 2; ++mt) {
        float part[4] = {0.f, 0.f, 0.f, 0.f};
#pragma unroll
        for (int nt = 0; nt < 4; ++nt) {
            int col = nt * 16 + lr;
            float bb = b1[col], w2 = W2[col];
#pragma unroll
            for (int rg = 0; rg < 4; ++rg) {
                float h = acc[mt][nt][rg] + bb;
                float cl = fminf(fmaxf(h, -15.f), 15.f);
                float e2 = __expf(2.f * cl);
                part[rg] += (e2 - 1.f) / (e2 + 1.f) * w2;
            }
        }
#pragma unroll
        for (int rg = 0; rg < 4; ++rg)
#pragma unroll
            for (int off = 1; off < 16; off <<= 1)
                part[rg] += __shfl_xor(part[rg], off, 64);
        if (lr == 0) {
#pragma unroll
            for (int rg = 0; rg < 4; ++rg) {
                int r = w * 32 + mt * 16 + lq * 4 + rg;
                int node = n0 + (r >> 2);
                if (node < NN) wout[(size_t)node * 4 + (r & 3)] = part[rg];
            }
        }
    }
}

// ---------------- softmax + weighted combine ----------------
__global__ __launch_bounds__(256) void att_combine(
    const float* __restrict__ x1, const unsigned short* __restrict__ x2b,
    const float* __restrict__ x3, const float* __restrict__ x4,
    const float* __restrict__ wsc, float* __restrict__ emb) {
    int node = blockIdx.x * 4 + (threadIdx.x >> 6);
    int lane = threadIdx.x & 63;
    float4 w = *(const float4*)(wsc + (size_t)node * 4);
    float m = fmaxf(fmaxf(w.x, w.y), fmaxf(w.z, w.w));
    float e0 = __expf(w.x - m), e1 = __expf(w.y - m), e2 = __expf(w.z - m), e3 = __expf(w.w - m);
    float inv = 1.f / (e0 + e1 + e2 + e3);
    float b0 = e0 * inv, b1 = e1 * inv, b2 = e2 * inv, b3 = e3 * inv;
    size_t base = (size_t)node * C + lane * 2;
    float2 z1 = *(const float2*)(x1 + base);
    ushort2 u2 = *(const ushort2*)(x2b + base);
    float2 z3 = *(const float2*)(x3 + base);
    float2 z4 = *(const float2*)(x4 + base);
    float2 o;
    o.x = b0 * z1.x + b1 * bf2f(u2.x) + b2 * z3.x + b3 * z4.x;
    o.y = b0 * z1.y + b1 * bf2f(u2.y) + b2 * z3.y + b3 * z4.y;
    *(float2*)(emb + base) = o;
}

extern "C" void kernel_launch(void* const* d_in, const int* in_sizes, int n_in,
                              void* d_out, int out_size, void* d_ws, size_t ws_size,
                              hipStream_t stream) {
    const float* x   = (const float*)d_in[0];
    const int* row   = (const int*)d_in[1];
    const int* col   = (const int*)d_in[2];
    const float* Wl0 = (const float*)d_in[3];
    const float* bl0 = (const float*)d_in[4];
    const float* Wr0 = (const float*)d_in[5];
    const float* Wl1 = (const float*)d_in[6];
    const float* bl1 = (const float*)d_in[7];
    const float* Wr1 = (const float*)d_in[8];
    const float* aW1 = (const float*)d_in[9];
    const float* ab1 = (const float*)d_in[10];
    const float* aW2 = (const float*)d_in[11];

    float* out = (float*)d_out;
    float* emb = out;                         // x1 fp32 lives here until att_combine overwrites
    float* x3  = out + (size_t)NN * C;
    float* x4  = out + 2 * (size_t)NN * C;

    char* ws = (char*)d_ws;
    size_t off = 0;
    auto alloc = [&](size_t bytes) -> void* {
        void* p = ws + off;
        off += (bytes + 255) & ~(size_t)255;
        return p;
    };
    int* deg     = (int*)alloc((size_t)NN * 4);
    int* offsets = (int*)alloc((size_t)(NN + 1) * 4);
    int* cursor  = (int*)alloc((size_t)NN * 4);
    int* bsum    = (int*)alloc((size_t)64 * 4);
    int* rowv    = (int*)alloc((size_t)NE * 4);
    int* colv    = (int*)alloc((size_t)NE * 4);
    float* n2    = (float*)alloc((size_t)NN * 4);
    float* s1    = (float*)alloc((size_t)NN * 4);
    float* n2_3  = (float*)alloc((size_t)NN * 4);
    float* s1_3  = (float*)alloc((size_t)NN * 4);
    float* n2_4  = (float*)alloc((size_t)NN * 4);
    float* s1_4  = (float*)alloc((size_t)NN * 4);
    float* wc    = (float*)alloc((size_t)NE * 4);   // reused for layer 2
    float* we    = (float*)alloc((size_t)NE * 4);   // reused for layer 2
    unsigned short* xbf   = (unsigned short*)alloc((size_t)NN * C * 2);  // reused as x1b
    unsigned short* aggcb = (unsigned short*)alloc((size_t)NN * C * 2);  // reused: agg1
    unsigned short* aggeb = (unsigned short*)alloc((size_t)NN * C * 2);  // reused: agg2
    unsigned short* x3b   = (unsigned short*)alloc((size_t)NN * C * 2);
    unsigned short* x4b   = (unsigned short*)alloc((size_t)NN * C * 2);
    unsigned short* x2b   = (unsigned short*)alloc((size_t)NN * C * 2);
    unsigned short* Bt    = (unsigned short*)alloc((size_t)65536 * 2);
    unsigned short* BtA   = (unsigned short*)alloc((size_t)8192 * 2);
    float* wout  = (float*)alloc((size_t)NN * 4 * 4);

    hipMemsetAsync(deg, 0, (size_t)NN * 4, stream);
    count_deg<<<(NE + 255) / 256, 256, 0, stream>>>(row, deg);
    deg_block_sums<<<SCAN_NB, 256, 0, stream>>>(deg, bsum);
    scan_bsums<<<1, 64, 0, stream>>>(bsum);
    scan_within<<<SCAN_NB, 256, 0, stream>>>(deg, bsum, offsets, cursor);
    bucket_edges<<<(NE + 255) / 256, 256, 0, stream>>>(row, col, cursor, rowv, colv);

    cast_x<<<(NN * C / 4 + 255) / 256, 256, 0, stream>>>(x, xbf);
    prep_w<<<256, 256, 0, stream>>>(Wl0, Wr0, Wl1, Wr1, Bt);
    prep_attw<<<32, 256, 0, stream>>>(aW1, BtA);

    stats_kernel<<<NN / 4, 256, 0, stream>>>(x, n2, s1);
    edge_sim1<<<NE / 16, 256, 0, stream>>>(xbf, rowv, colv, n2, s1, wc, we);
    agg_l1<<<NN / 4, 256, 0, stream>>>(xbf, colv, offsets, wc, we, aggcb, aggeb);

    const int GB = (NN + 127) / 128;
    gemm_mfma<<<GB, 256, 0, stream>>>(aggcb, xbf, Bt, bl0, x3, x3b, 1);
    gemm_mfma<<<GB, 256, 0, stream>>>(aggeb, xbf, Bt, bl0, x4, x4b, 1);

    stats_kernel<<<NN / 4, 256, 0, stream>>>(x3, n2_3, s1_3);
    stats_kernel<<<NN / 4, 256, 0, stream>>>(x4, n2_4, s1_4);
    edge_sim2<<<NE / 16, 256, 0, stream>>>(x3b, x4b, rowv, colv, n2_3, n2_4, s1_4, wc, we);
    agg_l2<<<NN / 4, 256, 0, stream>>>(x3b, x4b, colv, offsets, wc, we, aggcb, aggeb);

    gemm_mfma<<<GB, 256, 0, stream>>>(aggcb, x3b, Bt + 32768, bl1, emb, xbf /*x1b*/, 0);
    gemm_mfma<<<GB, 256, 0, stream>>>(aggeb, x4b, Bt + 32768, bl1, nullptr, x2b, 0);

    att_score<<<(NN + 31) / 32, 256, 0, stream>>>(xbf, x2b, x3b, x4b, BtA, ab1, aW2, wout);
    att_combine<<<NN / 4, 256, 0, stream>>>(emb, x2b, x3, x4, wout, emb);
}

// Round 7
// 538.523 us; speedup vs baseline: 3.3770x; 1.0320x over previous
//
#include <hip/hip_runtime.h>

#define NN 50000
#define NE 800000
#define C 128

typedef __attribute__((ext_vector_type(8))) short short8_t;
typedef __attribute__((ext_vector_type(4))) float f32x4;
typedef __attribute__((ext_vector_type(2))) _Float16 half2_t;
typedef __attribute__((ext_vector_type(8))) _Float16 half8_t;

__device__ __forceinline__ unsigned short f2h_u(float f) {
    _Float16 h = (_Float16)f;
    union { _Float16 h; unsigned short u; } v; v.h = h; return v.u;
}

__device__ __forceinline__ float fdot2(half2_t a, half2_t b, float c) {
#if __has_builtin(__builtin_amdgcn_fdot2)
    return __builtin_amdgcn_fdot2(a, b, c, false);
#else
    return c + (float)a.x * (float)b.x + (float)a.y * (float)b.y;
#endif
}

// ---------------- CSR build ----------------
__global__ void count_deg(const int* __restrict__ row, int* __restrict__ deg) {
    int e = blockIdx.x * blockDim.x + threadIdx.x;
    if (e < NE) atomicAdd(&deg[row[e]], 1);
}

#define SCAN_NB ((NN + 1023) / 1024)

__global__ void deg_block_sums(const int* __restrict__ deg, int* __restrict__ bsum) {
    __shared__ int sred[256];
    int t = threadIdx.x;
    int base = blockIdx.x * 1024 + t * 4;
    int s = 0;
    if (base + 3 < NN) {
        int4 v = *(const int4*)(deg + base);
        s = v.x + v.y + v.z + v.w;
    } else {
        for (int i = 0; i < 4; ++i) if (base + i < NN) s += deg[base + i];
    }
    sred[t] = s; __syncthreads();
    for (int off = 128; off > 0; off >>= 1) {
        if (t < off) sred[t] += sred[t + off];
        __syncthreads();
    }
    if (t == 0) bsum[blockIdx.x] = sred[0];
}

__global__ void scan_bsums(int* __restrict__ bsum) {   // 1 block x 64
    int t = threadIdx.x;
    int v = (t < SCAN_NB) ? bsum[t] : 0;
#pragma unroll
    for (int off = 1; off < 64; off <<= 1) {
        int u = __shfl_up(v, off, 64);
        if (t >= off) v += u;
    }
    int ex = __shfl_up(v, 1, 64);
    if (t == 0) ex = 0;
    if (t < SCAN_NB) bsum[t] = ex;
}

__global__ void scan_within(const int* __restrict__ deg, const int* __restrict__ bsum,
                            int* __restrict__ offsets, int* __restrict__ cursor) {
    __shared__ int sdat[256];
    int t = threadIdx.x;
    int base = blockIdx.x * 1024 + t * 4;
    int d[4] = {0, 0, 0, 0};
    if (base + 3 < NN) {
        int4 v = *(const int4*)(deg + base);
        d[0] = v.x; d[1] = v.y; d[2] = v.z; d[3] = v.w;
    } else {
        for (int i = 0; i < 4; ++i) if (base + i < NN) d[i] = deg[base + i];
    }
    sdat[t] = d[0] + d[1] + d[2] + d[3];
    __syncthreads();
    for (int off = 1; off < 256; off <<= 1) {
        int v = sdat[t];
        int add = (t >= off) ? sdat[t - off] : 0;
        __syncthreads();
        sdat[t] = v + add;
        __syncthreads();
    }
    int run = bsum[blockIdx.x] + ((t == 0) ? 0 : sdat[t - 1]);
    for (int i = 0; i < 4; ++i) {
        int idx = base + i;
        if (idx < NN) { offsets[idx] = run; cursor[idx] = run; run += d[i]; }
    }
    if (blockIdx.x == 0 && t == 0) offsets[NN] = NE;
}

__global__ void bucket_edges(const int* __restrict__ row, const int* __restrict__ col,
                             int* __restrict__ cursor, int* __restrict__ rowv,
                             int* __restrict__ colv) {
    int e = blockIdx.x * blockDim.x + threadIdx.x;
    if (e < NE) {
        int r = row[e];
        int p = atomicAdd(&cursor[r], 1);
        rowv[p] = r;
        colv[p] = col[e];
    }
}

// ---------------- cast x -> fp16 AND per-node stats in one pass ----------------
__global__ void cast_stats(const float* __restrict__ x, unsigned short* __restrict__ xh,
                           float* __restrict__ n2, float* __restrict__ s1) {
    int node = blockIdx.x * 4 + (threadIdx.x >> 6);
    int lane = threadIdx.x & 63;
    float2 v = *(const float2*)(x + (size_t)node * C + lane * 2);
    half2_t h; h.x = (_Float16)v.x; h.y = (_Float16)v.y;
    *(half2_t*)(xh + (size_t)node * C + lane * 2) = h;
    float sq = v.x * v.x + v.y * v.y;
    float sm = v.x + v.y;
#pragma unroll
    for (int off = 32; off > 0; off >>= 1) {
        sq += __shfl_xor(sq, off, 64);
        sm += __shfl_xor(sm, off, 64);
    }
    if (lane == 0) { n2[node] = sq; s1[node] = sm; }
}

// ---------------- layer-2 stats (x3: n2 only; x4: n2+s1), fused ----------------
__global__ void stats2(const float* __restrict__ x3, const float* __restrict__ x4,
                       float* __restrict__ n2_3, float* __restrict__ n2_4,
                       float* __restrict__ s1_4) {
    int node = blockIdx.x * 4 + (threadIdx.x >> 6);
    int lane = threadIdx.x & 63;
    float2 a = *(const float2*)(x3 + (size_t)node * C + lane * 2);
    float2 b = *(const float2*)(x4 + (size_t)node * C + lane * 2);
    float q3 = a.x * a.x + a.y * a.y;
    float q4 = b.x * b.x + b.y * b.y;
    float m4 = b.x + b.y;
#pragma unroll
    for (int off = 32; off > 0; off >>= 1) {
        q3 += __shfl_xor(q3, off, 64);
        q4 += __shfl_xor(q4, off, 64);
        m4 += __shfl_xor(m4, off, 64);
    }
    if (lane == 0) { n2_3[node] = q3; n2_4[node] = q4; s1_4[node] = m4; }
}

// ---------------- weight prep (GEMM weights + attention W1), fused ----------------
__global__ void prep_weights(const float* __restrict__ Wl0, const float* __restrict__ Wr0,
                             const float* __restrict__ Wl1, const float* __restrict__ Wr1,
                             const float* __restrict__ aW1,
                             unsigned short* __restrict__ Bt, unsigned short* __restrict__ BtA) {
    int id = blockIdx.x * 256 + threadIdx.x;   // [0, 65536+8192)
    if (id < 65536) {
        int layer = id >> 15;
        int c = (id >> 14) & 1;
        int n = (id >> 7) & 127;
        int kk = id & 127;
        const float* W = layer == 0 ? (c == 0 ? Wl0 : Wr0) : (c == 0 ? Wl1 : Wr1);
        Bt[id] = f2h_u(W[kk * 128 + n]);
    } else {
        int a = id - 65536;                    // [0, 8192)
        int col = a >> 7, k = a & 127;
        BtA[a] = f2h_u(aW1[k * 64 + col]);
    }
}

// ---------------- edge similarity (layer 1): fp16 rows, v_dot2 ----------------
__global__ __launch_bounds__(256) void edge_sim1(
    const unsigned short* __restrict__ xh, const int* __restrict__ rowv,
    const int* __restrict__ colv, const float* __restrict__ n2, const float* __restrict__ s1,
    float* __restrict__ wc, float* __restrict__ we) {
    int p = blockIdx.x * 16 + (threadIdx.x >> 4);
    int lr = threadIdx.x & 15;
    int r = rowv[p], c = colv[p];
    half8_t ar = *(const half8_t*)(xh + (size_t)r * C + lr * 8);
    half8_t ac = *(const half8_t*)(xh + (size_t)c * C + lr * 8);
    float dp = 0.f;
#pragma unroll
    for (int i = 0; i < 4; ++i) {
        half2_t a; a.x = ar[2 * i]; a.y = ar[2 * i + 1];
        half2_t b; b.x = ac[2 * i]; b.y = ac[2 * i + 1];
        dp = fdot2(a, b, dp);
    }
#pragma unroll
    for (int off = 1; off < 16; off <<= 1) dp += __shfl_xor(dp, off, 64);
    if (lr == 0) {
        float n2r = n2[r], n2c = n2[c];
        wc[p] = dp / fmaxf(sqrtf(n2r * n2c), 1e-8f);
        float d2 = n2r + n2c - 2.f * dp + 2e-6f * (s1[r] - s1[c]) + 1.28e-10f;
        we[p] = sqrtf(fmaxf(d2, 0.f));
    }
}

// ---------------- edge similarity (layer 2): fp16 dots over x3h (cos) and x4h (eud) ----------------
__global__ __launch_bounds__(256) void edge_sim2(
    const unsigned short* __restrict__ x3h, const unsigned short* __restrict__ x4h,
    const int* __restrict__ rowv, const int* __restrict__ colv,
    const float* __restrict__ n2_3, const float* __restrict__ n2_4,
    const float* __restrict__ s1_4, float* __restrict__ wc, float* __restrict__ we) {
    int p = blockIdx.x * 16 + (threadIdx.x >> 4);
    int lr = threadIdx.x & 15;
    int r = rowv[p], c = colv[p];
    half8_t a3 = *(const half8_t*)(x3h + (size_t)r * C + lr * 8);
    half8_t b3 = *(const half8_t*)(x3h + (size_t)c * C + lr * 8);
    half8_t a4 = *(const half8_t*)(x4h + (size_t)r * C + lr * 8);
    half8_t b4 = *(const half8_t*)(x4h + (size_t)c * C + lr * 8);
    float dp3 = 0.f, dp4 = 0.f;
#pragma unroll
    for (int i = 0; i < 4; ++i) {
        half2_t p3; p3.x = a3[2 * i]; p3.y = a3[2 * i + 1];
        half2_t q3; q3.x = b3[2 * i]; q3.y = b3[2 * i + 1];
        dp3 = fdot2(p3, q3, dp3);
        half2_t p4; p4.x = a4[2 * i]; p4.y = a4[2 * i + 1];
        half2_t q4; q4.x = b4[2 * i]; q4.y = b4[2 * i + 1];
        dp4 = fdot2(p4, q4, dp4);
    }
#pragma unroll
    for (int off = 1; off < 16; off <<= 1) {
        dp3 += __shfl_xor(dp3, off, 64);
        dp4 += __shfl_xor(dp4, off, 64);
    }
    if (lr == 0) {
        wc[p] = dp3 / fmaxf(sqrtf(n2_3[r] * n2_3[c]), 1e-8f);
        float d2 = n2_4[r] + n2_4[c] - 2.f * dp4 + 2e-6f * (s1_4[r] - s1_4[c]) + 1.28e-10f;
        we[p] = sqrtf(fmaxf(d2, 0.f));
    }
}

// ---------------- weighted gather-aggregate (layer 1): fp16 gather, both weights ----------------
__global__ __launch_bounds__(256) void agg_l1(
    const unsigned short* __restrict__ xh, const int* __restrict__ colv,
    const int* __restrict__ offsets, const float* __restrict__ wc, const float* __restrict__ we,
    unsigned short* __restrict__ aggc, unsigned short* __restrict__ agge) {
    int node = blockIdx.x * 4 + (threadIdx.x >> 6);
    int lane = threadIdx.x & 63;
    int beg = offsets[node], end = offsets[node + 1];
    float ac0 = 0.f, ac1 = 0.f, ae0 = 0.f, ae1 = 0.f;
    int p = beg;
    for (; p + 3 < end; p += 4) {
        int c0 = colv[p], c1 = colv[p + 1], c2 = colv[p + 2], c3 = colv[p + 3];
        half2_t u0 = *(const half2_t*)(xh + (size_t)c0 * C + lane * 2);
        half2_t u1 = *(const half2_t*)(xh + (size_t)c1 * C + lane * 2);
        half2_t u2 = *(const half2_t*)(xh + (size_t)c2 * C + lane * 2);
        half2_t u3 = *(const half2_t*)(xh + (size_t)c3 * C + lane * 2);
        float wc0 = wc[p], wc1 = wc[p + 1], wc2 = wc[p + 2], wc3 = wc[p + 3];
        float we0 = we[p], we1 = we[p + 1], we2 = we[p + 2], we3 = we[p + 3];
        float v0x = (float)u0.x, v0y = (float)u0.y;
        float v1x = (float)u1.x, v1y = (float)u1.y;
        float v2x = (float)u2.x, v2y = (float)u2.y;
        float v3x = (float)u3.x, v3y = (float)u3.y;
        ac0 += wc0 * v0x + wc1 * v1x + wc2 * v2x + wc3 * v3x;
        ac1 += wc0 * v0y + wc1 * v1y + wc2 * v2y + wc3 * v3y;
        ae0 += we0 * v0x + we1 * v1x + we2 * v2x + we3 * v3x;
        ae1 += we0 * v0y + we1 * v1y + we2 * v2y + we3 * v3y;
    }
    for (; p < end; ++p) {
        int c0 = colv[p];
        half2_t u0 = *(const half2_t*)(xh + (size_t)c0 * C + lane * 2);
        float wc0 = wc[p], we0 = we[p];
        float v0x = (float)u0.x, v0y = (float)u0.y;
        ac0 += wc0 * v0x; ac1 += wc0 * v0y;
        ae0 += we0 * v0x; ae1 += we0 * v0y;
    }
    float inv = 1.f / fmaxf((float)(end - beg), 1.f);
    ushort2 uc; uc.x = f2h_u(ac0 * inv); uc.y = f2h_u(ac1 * inv);
    ushort2 ue; ue.x = f2h_u(ae0 * inv); ue.y = f2h_u(ae1 * inv);
    *(ushort2*)(aggc + (size_t)node * C + lane * 2) = uc;
    *(ushort2*)(agge + (size_t)node * C + lane * 2) = ue;
}

// ---------------- weighted gather-aggregate (layer 2): fp16 gathers, wc x3h, we x4h ----------------
__global__ __launch_bounds__(256) void agg_l2(
    const unsigned short* __restrict__ x3h, const unsigned short* __restrict__ x4h,
    const int* __restrict__ colv, const int* __restrict__ offsets,
    const float* __restrict__ wc, const float* __restrict__ we,
    unsigned short* __restrict__ agg1, unsigned short* __restrict__ agg2) {
    int node = blockIdx.x * 4 + (threadIdx.x >> 6);
    int lane = threadIdx.x & 63;
    int beg = offsets[node], end = offsets[node + 1];
    float a10 = 0.f, a11 = 0.f, a20 = 0.f, a21 = 0.f;
    int p = beg;
    for (; p + 1 < end; p += 2) {
        int c0 = colv[p], c1 = colv[p + 1];
        half2_t u0 = *(const half2_t*)(x3h + (size_t)c0 * C + lane * 2);
        half2_t u1 = *(const half2_t*)(x3h + (size_t)c1 * C + lane * 2);
        half2_t v0 = *(const half2_t*)(x4h + (size_t)c0 * C + lane * 2);
        half2_t v1 = *(const half2_t*)(x4h + (size_t)c1 * C + lane * 2);
        float wc0 = wc[p], wc1 = wc[p + 1], we0 = we[p], we1 = we[p + 1];
        a10 += wc0 * (float)u0.x + wc1 * (float)u1.x;
        a11 += wc0 * (float)u0.y + wc1 * (float)u1.y;
        a20 += we0 * (float)v0.x + we1 * (float)v1.x;
        a21 += we0 * (float)v0.y + we1 * (float)v1.y;
    }
    if (p < end) {
        int c0 = colv[p];
        half2_t u0 = *(const half2_t*)(x3h + (size_t)c0 * C + lane * 2);
        half2_t v0 = *(const half2_t*)(x4h + (size_t)c0 * C + lane * 2);
        float wc0 = wc[p], we0 = we[p];
        a10 += wc0 * (float)u0.x; a11 += wc0 * (float)u0.y;
        a20 += we0 * (float)v0.x; a21 += we0 * (float)v0.y;
    }
    float inv = 1.f / fmaxf((float)(end - beg), 1.f);
    ushort2 u1o; u1o.x = f2h_u(a10 * inv); u1o.y = f2h_u(a11 * inv);
    ushort2 u2o; u2o.x = f2h_u(a20 * inv); u2o.y = f2h_u(a21 * inv);
    *(ushort2*)(agg1 + (size_t)node * C + lane * 2) = u1o;
    *(ushort2*)(agg2 + (size_t)node * C + lane * 2) = u2o;
}

// ---------------- MFMA GEMM (f16): C[n,128] = [A0|A1](n, 256) @ B(256,128) + bias ----------------
__global__ __launch_bounds__(256) void gemm_mfma(
    const unsigned short* __restrict__ A0, const unsigned short* __restrict__ A1,
    const unsigned short* __restrict__ Bt, const float* __restrict__ bias,
    float* __restrict__ Cout, unsigned short* __restrict__ Chf, int relu) {
    __shared__ __align__(16) unsigned short sA[128 * 136];
    __shared__ __align__(16) unsigned short sB[128 * 136];
    const int tx = threadIdx.x;
    const int l = tx & 63;
    const int wv = tx >> 6;
    const int wm = wv >> 1, wn = wv & 1;
    const int lr = l & 15;
    const int lq = l >> 4;
    const int n0 = blockIdx.x * 128;

    f32x4 acc[4][4] = {};
    for (int c = 0; c < 2; ++c) {
        const unsigned short* Ac = (c == 0) ? A0 : A1;
#pragma unroll
        for (int it = 0; it < 8; ++it) {
            int idx = it * 256 + tx;
            int r = idx >> 4, s = idx & 15;
            int n = n0 + r; n = n < NN ? n : NN - 1;
            *(short8_t*)(sA + r * 136 + s * 8) = *(const short8_t*)(Ac + (size_t)n * 128 + s * 8);
            *(short8_t*)(sB + r * 136 + s * 8) = *(const short8_t*)(Bt + c * 16384 + idx * 8);
        }
        __syncthreads();
#pragma unroll
        for (int ks = 0; ks < 4; ++ks) {
            half8_t af[4], bfr[4];
#pragma unroll
            for (int t = 0; t < 4; ++t) {
                af[t]  = *(const half8_t*)(sA + (wm * 64 + t * 16 + lr) * 136 + ks * 32 + lq * 8);
                bfr[t] = *(const half8_t*)(sB + (wn * 64 + t * 16 + lr) * 136 + ks * 32 + lq * 8);
            }
#pragma unroll
            for (int mt = 0; mt < 4; ++mt)
#pragma unroll
                for (int nt = 0; nt < 4; ++nt)
                    acc[mt][nt] = __builtin_amdgcn_mfma_f32_16x16x32_f16(af[mt], bfr[nt], acc[mt][nt], 0, 0, 0);
        }
        __syncthreads();
    }
#pragma unroll
    for (int mt = 0; mt < 4; ++mt) {
        int rbase = wm * 64 + mt * 16 + lq * 4;
#pragma unroll
        for (int nt = 0; nt < 4; ++nt) {
            int col = wn * 64 + nt * 16 + lr;
            float bv = bias[col];
#pragma unroll
            for (int rg = 0; rg < 4; ++rg) {
                int n = n0 + rbase + rg;
                if (n < NN) {
                    float y = acc[mt][nt][rg] + bv;
                    if (relu) y = fmaxf(y, 0.f);
                    if (Cout) Cout[(size_t)n * 128 + col] = y;
                    if (Chf) Chf[(size_t)n * 128 + col] = f2h_u(y);
                }
            }
        }
    }
}

// ---------------- attention scores via MFMA (f16) ----------------
__global__ __launch_bounds__(256) void att_score(
    const unsigned short* __restrict__ x1h, const unsigned short* __restrict__ x2h,
    const unsigned short* __restrict__ x3h, const unsigned short* __restrict__ x4h,
    const unsigned short* __restrict__ BtA, const float* __restrict__ b1,
    const float* __restrict__ W2, float* __restrict__ wout) {
    __shared__ __align__(16) unsigned short sA[128 * 136];
    __shared__ __align__(16) unsigned short sB[64 * 136];
    const int tx = threadIdx.x;
    const int n0 = blockIdx.x * 32;
    const unsigned short* zb[4] = {x1h, x2h, x3h, x4h};
#pragma unroll
    for (int it = 0; it < 8; ++it) {
        int idx = it * 256 + tx;
        int r = idx >> 4, s = idx & 15;
        int node = n0 + (r >> 2); node = node < NN ? node : NN - 1;
        *(short8_t*)(sA + r * 136 + s * 8) = *(const short8_t*)(zb[r & 3] + (size_t)node * 128 + s * 8);
    }
#pragma unroll
    for (int it = 0; it < 4; ++it) {
        int idx = it * 256 + tx;
        int r = idx >> 4, s = idx & 15;
        *(short8_t*)(sB + r * 136 + s * 8) = *(const short8_t*)(BtA + idx * 8);
    }
    __syncthreads();
    const int w = tx >> 6, lane = tx & 63, lr = lane & 15, lq = lane >> 4;
    f32x4 acc[2][4] = {};
#pragma unroll
    for (int ks = 0; ks < 4; ++ks) {
        half8_t af[2], bfr[4];
#pragma unroll
        for (int mt = 0; mt < 2; ++mt)
            af[mt] = *(const half8_t*)(sA + (w * 32 + mt * 16 + lr) * 136 + ks * 32 + lq * 8);
#pragma unroll
        for (int nt = 0; nt < 4; ++nt)
            bfr[nt] = *(const half8_t*)(sB + (nt * 16 + lr) * 136 + ks * 32 + lq * 8);
#pragma unroll
        for (int mt = 0; mt < 2; ++mt)
#pragma unroll
            for (int nt = 0; nt < 4; ++nt)
                acc[mt][nt] = __builtin_amdgcn_mfma_f32_16x16x32_f16(af[mt], bfr[nt], acc[mt][nt], 0, 0, 0);
    }
#pragma unroll
    for (int mt = 0; mt < 2; ++mt) {
        float part[4] = {0.f, 0.f, 0.f, 0.f};
#pragma unroll
        for (int nt = 0; nt < 4; ++nt) {
            int col = nt * 16 + lr;
            float bb = b1[col], w2 = W2[col];
#pragma unroll
            for (int rg = 0; rg < 4; ++rg) {
                float h = acc[mt][nt][rg] + bb;
                float cl = fminf(fmaxf(h, -15.f), 15.f);
                float e2 = __expf(2.f * cl);
                part[rg] += (e2 - 1.f) / (e2 + 1.f) * w2;
            }
        }
#pragma unroll
        for (int rg = 0; rg < 4; ++rg)
#pragma unroll
            for (int off = 1; off < 16; off <<= 1)
                part[rg] += __shfl_xor(part[rg], off, 64);
        if (lr == 0) {
#pragma unroll
            for (int rg = 0; rg < 4; ++rg) {
                int r = w * 32 + mt * 16 + lq * 4 + rg;
                int node = n0 + (r >> 2);
                if (node < NN) wout[(size_t)node * 4 + (r & 3)] = part[rg];
            }
        }
    }
}

// ---------------- softmax + weighted combine ----------------
__global__ __launch_bounds__(256) void att_combine(
    const float* __restrict__ x1, const unsigned short* __restrict__ x2h,
    const float* __restrict__ x3, const float* __restrict__ x4,
    const float* __restrict__ wsc, float* __restrict__ emb) {
    int node = blockIdx.x * 4 + (threadIdx.x >> 6);
    int lane = threadIdx.x & 63;
    float4 w = *(const float4*)(wsc + (size_t)node * 4);
    float m = fmaxf(fmaxf(w.x, w.y), fmaxf(w.z, w.w));
    float e0 = __expf(w.x - m), e1 = __expf(w.y - m), e2 = __expf(w.z - m), e3 = __expf(w.w - m);
    float inv = 1.f / (e0 + e1 + e2 + e3);
    float b0 = e0 * inv, b1 = e1 * inv, b2 = e2 * inv, b3 = e3 * inv;
    size_t base = (size_t)node * C + lane * 2;
    float2 z1 = *(const float2*)(x1 + base);
    half2_t u2 = *(const half2_t*)(x2h + base);
    float2 z3 = *(const float2*)(x3 + base);
    float2 z4 = *(const float2*)(x4 + base);
    float2 o;
    o.x = b0 * z1.x + b1 * (float)u2.x + b2 * z3.x + b3 * z4.x;
    o.y = b0 * z1.y + b1 * (float)u2.y + b2 * z3.y + b3 * z4.y;
    *(float2*)(emb + base) = o;
}

extern "C" void kernel_launch(void* const* d_in, const int* in_sizes, int n_in,
                              void* d_out, int out_size, void* d_ws, size_t ws_size,
                              hipStream_t stream) {
    const float* x   = (const float*)d_in[0];
    const int* row   = (const int*)d_in[1];
    const int* col   = (const int*)d_in[2];
    const float* Wl0 = (const float*)d_in[3];
    const float* bl0 = (const float*)d_in[4];
    const float* Wr0 = (const float*)d_in[5];
    const float* Wl1 = (const float*)d_in[6];
    const float* bl1 = (const float*)d_in[7];
    const float* Wr1 = (const float*)d_in[8];
    const float* aW1 = (const float*)d_in[9];
    const float* ab1 = (const float*)d_in[10];
    const float* aW2 = (const float*)d_in[11];

    float* out = (float*)d_out;
    float* emb = out;                         // x1 fp32 lives here until att_combine overwrites
    float* x3  = out + (size_t)NN * C;
    float* x4  = out + 2 * (size_t)NN * C;

    char* ws = (char*)d_ws;
    size_t off = 0;
    auto alloc = [&](size_t bytes) -> void* {
        void* p = ws + off;
        off += (bytes + 255) & ~(size_t)255;
        return p;
    };
    int* deg     = (int*)alloc((size_t)NN * 4);
    int* offsets = (int*)alloc((size_t)(NN + 1) * 4);
    int* cursor  = (int*)alloc((size_t)NN * 4);
    int* bsum    = (int*)alloc((size_t)64 * 4);
    int* rowv    = (int*)alloc((size_t)NE * 4);
    int* colv    = (int*)alloc((size_t)NE * 4);
    float* n2    = (float*)alloc((size_t)NN * 4);
    float* s1    = (float*)alloc((size_t)NN * 4);
    float* n2_3  = (float*)alloc((size_t)NN * 4);
    float* n2_4  = (float*)alloc((size_t)NN * 4);
    float* s1_4  = (float*)alloc((size_t)NN * 4);
    float* wc    = (float*)alloc((size_t)NE * 4);   // reused for layer 2
    float* we    = (float*)alloc((size_t)NE * 4);   // reused for layer 2
    unsigned short* xh    = (unsigned short*)alloc((size_t)NN * C * 2);  // reused as x1h
    unsigned short* aggch = (unsigned short*)alloc((size_t)NN * C * 2);  // reused: agg1
    unsigned short* aggeh = (unsigned short*)alloc((size_t)NN * C * 2);  // reused: agg2
    unsigned short* x3h   = (unsigned short*)alloc((size_t)NN * C * 2);
    unsigned short* x4h   = (unsigned short*)alloc((size_t)NN * C * 2);
    unsigned short* x2h   = (unsigned short*)alloc((size_t)NN * C * 2);
    unsigned short* Bt    = (unsigned short*)alloc((size_t)65536 * 2);
    unsigned short* BtA   = (unsigned short*)alloc((size_t)8192 * 2);
    float* wout  = (float*)alloc((size_t)NN * 4 * 4);

    hipMemsetAsync(deg, 0, (size_t)NN * 4, stream);
    count_deg<<<(NE + 255) / 256, 256, 0, stream>>>(row, deg);
    deg_block_sums<<<SCAN_NB, 256, 0, stream>>>(deg, bsum);
    scan_bsums<<<1, 64, 0, stream>>>(bsum);
    scan_within<<<SCAN_NB, 256, 0, stream>>>(deg, bsum, offsets, cursor);
    bucket_edges<<<(NE + 255) / 256, 256, 0, stream>>>(row, col, cursor, rowv, colv);

    cast_stats<<<NN / 4, 256, 0, stream>>>(x, xh, n2, s1);
    prep_weights<<<(65536 + 8192) / 256, 256, 0, stream>>>(Wl0, Wr0, Wl1, Wr1, aW1, Bt, BtA);

    edge_sim1<<<NE / 16, 256, 0, stream>>>(xh, rowv, colv, n2, s1, wc, we);
    agg_l1<<<NN / 4, 256, 0, stream>>>(xh, colv, offsets, wc, we, aggch, aggeh);

    const int GB = (NN + 127) / 128;
    gemm_mfma<<<GB, 256, 0, stream>>>(aggch, xh, Bt, bl0, x3, x3h, 1);
    gemm_mfma<<<GB, 256, 0, stream>>>(aggeh, xh, Bt, bl0, x4, x4h, 1);

    stats2<<<NN / 4, 256, 0, stream>>>(x3, x4, n2_3, n2_4, s1_4);
    edge_sim2<<<NE / 16, 256, 0, stream>>>(x3h, x4h, rowv, colv, n2_3, n2_4, s1_4, wc, we);
    agg_l2<<<NN / 4, 256, 0, stream>>>(x3h, x4h, colv, offsets, wc, we, aggch, aggeh);

    gemm_mfma<<<GB, 256, 0, stream>>>(aggch, x3h, Bt + 32768, bl1, emb, xh /*x1h*/, 0);
    gemm_mfma<<<GB, 256, 0, stream>>>(aggeh, x4h, Bt + 32768, bl1, nullptr, x2h, 0);

    att_score<<<(NN + 31) / 32, 256, 0, stream>>>(xh, x2h, x3h, x4h, BtA, ab1, aW2, wout);
    att_combine<<<NN / 4, 256, 0, stream>>>(emb, x2h, x3, x4, wout, emb);
}